// Round 13
// baseline (317.112 us; speedup 1.0000x reference)
//
#include <hip/hip_runtime.h>
#include <hip/hip_bf16.h>

#define N_NODES 50000
#define N_EDGES 800000
#define EP (N_EDGES + N_NODES)
#define N_GRAPHS 64
#define F_DIM 128
#define OUT_DIM 10
#define NB 391                   // dst buckets of 128
#define NREP 8                   // cursor replicas: rep = blockIdx & 7
#define SUBCAP 384               // per (bucket,rep): E=256, +8 sigma
#define EIDS_CAP 2560            // per-bucket: E=2174 (incl selfloops), +8.6 sigma
#define SC_EDGES 4096            // edges per scatter block
#define SC_BLOCKS ((N_EDGES + SC_EDGES - 1) / SC_EDGES)   // 196
#define POOL_CHUNK 128
#define POOL_BLOCKS ((N_NODES + POOL_CHUNK - 1) / POOL_CHUNK) // 391

typedef __attribute__((ext_vector_type(8))) short short8;
typedef __attribute__((ext_vector_type(4))) float f32x4;

__device__ __forceinline__ unsigned int f2bf(float f) {
    unsigned int x; __builtin_memcpy(&x, &f, 4);
    return (x + 0x7fffu + ((x >> 16) & 1u)) >> 16;          // RNE
}
__device__ __forceinline__ float bf2f(unsigned int u16) {
    unsigned int x = u16 << 16;
    float f; __builtin_memcpy(&f, &x, 4); return f;
}

// ---------------- prep: zeros + W->Wt casts + weff_d ----------------

__global__ __launch_bounds__(256) void prep_kernel(
    const float* __restrict__ W1, const float* __restrict__ W2,
    const float* __restrict__ Wd1, const float* __restrict__ ad1,
    const float* __restrict__ Wd2, const float* __restrict__ ad2,
    unsigned short* __restrict__ Wt1, unsigned short* __restrict__ Wt2,
    float* __restrict__ weffd1, float* __restrict__ weffd2,
    uint4* __restrict__ zero_bcur /*782*/, uint4* __restrict__ zero_sums /*2064: sums+counter*/) {
    int tid = blockIdx.x * 256 + threadIdx.x;
    if (tid < 782) zero_bcur[tid] = make_uint4(0, 0, 0, 0);
    else if (tid < 782 + 2064) zero_sums[tid - 782] = make_uint4(0, 0, 0, 0);
    if (tid < 512) {
        const float* Wd = (tid < 256) ? Wd1 : Wd2;
        const float* ad = (tid < 256) ? ad1 : ad2;
        float* wout = (tid < 256) ? weffd1 : weffd2;
        int i = tid & 255, f = i >> 1, h = i & 1;
        const float4* wr = (const float4*)(Wd + f * 128 + h * 64);
        const float4* av = (const float4*)(ad + h * 64);
        float s = 0.f;
        #pragma unroll
        for (int c = 0; c < 16; ++c) {
            float4 w = wr[c], a = av[c];
            s += w.x*a.x + w.y*a.y + w.z*a.z + w.w*a.w;
        }
        wout[f * 2 + h] = s;
    }
    const float* W = (tid < 16384) ? W1 : W2;
    unsigned short* Wt = (tid < 16384) ? Wt1 : Wt2;
    int i = tid & 16383;
    int k = i >> 7, nn = i & 127;
    Wt[nn * 128 + k] = (unsigned short)f2bf(W[i]);
}

// ---------------- CSR build: LDS counting-sort scatter (coalesced run writes) ----------------

__global__ __launch_bounds__(1024) void scatter_kernel(const int* __restrict__ ei,
                                                       int* __restrict__ bcursor,
                                                       unsigned int* __restrict__ recs) {
    __shared__ unsigned int srec[SC_EDGES];   // 16 KB
    __shared__ int hist[NB], lcur[NB], gpos[NB];
    __shared__ int excl[512];
    int t = threadIdx.x;
    int base = blockIdx.x * SC_EDGES;
    int rep = blockIdx.x & (NREP - 1);
    for (int i = t; i < NB; i += 1024) { hist[i] = 0; lcur[i] = 0; }
    __syncthreads();
    unsigned int rec_[4]; int have[4];
    #pragma unroll
    for (int j = 0; j < 4; ++j) {
        int i = base + j * 1024 + t;
        have[j] = (i < N_EDGES);
        if (have[j]) {
            int src = ei[i], dst = ei[N_EDGES + i];
            int b = dst >> 7;
            rec_[j] = ((unsigned)b << 23) | ((unsigned)(dst & 127) << 16) | (unsigned)src;
            atomicAdd(&hist[b], 1);
        }
    }
    __syncthreads();
    if (t < 512) excl[t] = (t < NB) ? hist[t] : 0;
    __syncthreads();
    for (int off = 1; off < 512; off <<= 1) {
        int v = 0;
        if (t < 512 && t >= off) v = excl[t - off];
        __syncthreads();
        if (t < 512) excl[t] += v;
        __syncthreads();
    }
    if (t < NB && hist[t] > 0) gpos[t] = atomicAdd(&bcursor[rep * NB + t], hist[t]);
    __syncthreads();
    #pragma unroll
    for (int j = 0; j < 4; ++j) {
        if (have[j]) {
            int b = rec_[j] >> 23;
            int pos = atomicAdd(&lcur[b], 1);
            srec[(excl[b] - hist[b]) + pos] = rec_[j];
        }
    }
    __syncthreads();
    int cnt = N_EDGES - base; if (cnt > SC_EDGES) cnt = SC_EDGES;
    for (int i = t; i < cnt; i += 1024) {
        unsigned int rec = srec[i];
        int b = rec >> 23;
        int gp = gpos[b] + (i - (excl[b] - hist[b]));
        if (gp < SUBCAP)
            recs[((size_t)b * NREP + rep) * SUBCAP + gp] = rec & 0x7fffffu;
    }
}

// one block per bucket: concat 8 sub-segments + inject self-loops -> eids + (start,end)
__global__ __launch_bounds__(256) void bucketize_kernel(
    const unsigned int* __restrict__ recs, const int* __restrict__ bcursor,
    unsigned short* __restrict__ eids, int2* __restrict__ rsre, int n) {
    __shared__ int ssub[NREP + 1];
    __shared__ int hist[128], excl[128], cur[128];
    __shared__ unsigned int srec[EIDS_CAP];
    int b = blockIdx.x, t = threadIdx.x;
    int nvalid = n - b * 128; if (nvalid > 128) nvalid = 128;
    if (t < 128) { hist[t] = 0; cur[t] = 0; }
    if (t == 0) {
        int run = 0; ssub[0] = 0;
        for (int r = 0; r < NREP; ++r) {
            int c = bcursor[r * NB + b]; if (c > SUBCAP) c = SUBCAP;
            run += c; ssub[r + 1] = run;
        }
    }
    __syncthreads();
    int total = ssub[NREP];
    int maxsc = EIDS_CAP - 128;
    if (total > maxsc) total = maxsc;
    const unsigned int* rb = recs + (size_t)b * NREP * SUBCAP;
    for (int i = t; i < total; i += 256) {
        int r = 0;
        while (ssub[r + 1] <= i) ++r;
        unsigned int rec = rb[r * SUBCAP + (i - ssub[r])];
        srec[i] = rec;
        atomicAdd(&hist[(rec >> 16) & 127], 1);
    }
    __syncthreads();
    if (t < nvalid) hist[t] += 1;                    // self loop
    __syncthreads();
    if (t < 128) excl[t] = hist[t];
    __syncthreads();
    for (int off = 1; off < 128; off <<= 1) {
        int v = 0;
        if (t < 128 && t >= off) v = excl[t - off];
        __syncthreads();
        if (t < 128) excl[t] += v;
        __syncthreads();
    }
    int base2 = b * EIDS_CAP;
    if (t < nvalid) {
        int st = excl[t] - hist[t];
        rsre[b * 128 + t] = make_int2(base2 + st, base2 + excl[t]);
        eids[base2 + st] = (unsigned short)(b * 128 + t);
        cur[t] = 1;
    }
    __syncthreads();
    for (int i = t; i < total; i += 256) {
        unsigned int rec = srec[i];
        int dl = (rec >> 16) & 127;
        int pos = atomicAdd(&cur[dl], 1);
        eids[base2 + (excl[dl] - hist[dl]) + pos] = (unsigned short)(rec & 0xffffu);
    }
}

// ---------------- fused MFMA GEMM + attention scalars ----------------

__global__ __launch_bounds__(256) void gemm_fused_f32a_kernel(
    const float* __restrict__ A, const unsigned short* __restrict__ Wt,
    const float* __restrict__ att_s, const float* __restrict__ weffd,
    unsigned short* __restrict__ C, float* __restrict__ a_s, float* __restrict__ a_d, int n) {
    int t = threadIdx.x;
    int l = t & 63;
    int quad = l >> 4, lr = l & 15;
    int m0 = blockIdx.x * 64 + (t >> 6) * 16;
    int arow = m0 + lr; if (arow >= n) arow = n - 1;

    short8 afrag[4];
    float pd0 = 0.f, pd1 = 0.f;
    const float2* wd2 = (const float2*)weffd;
    #pragma unroll
    for (int kb = 0; kb < 4; ++kb) {
        const float4* ap = (const float4*)(A + (size_t)arow * 128 + kb * 32 + quad * 8);
        float4 a0 = ap[0], a1 = ap[1];
        int k0 = kb * 32 + quad * 8;
        float2 w0 = wd2[k0+0], w1 = wd2[k0+1], w2 = wd2[k0+2], w3 = wd2[k0+3];
        float2 w4 = wd2[k0+4], w5 = wd2[k0+5], w6 = wd2[k0+6], w7 = wd2[k0+7];
        pd0 += a0.x*w0.x + a0.y*w1.x + a0.z*w2.x + a0.w*w3.x
             + a1.x*w4.x + a1.y*w5.x + a1.z*w6.x + a1.w*w7.x;
        pd1 += a0.x*w0.y + a0.y*w1.y + a0.z*w2.y + a0.w*w3.y
             + a1.x*w4.y + a1.y*w5.y + a1.z*w6.y + a1.w*w7.y;
        short8 s;
        s[0] = (short)f2bf(a0.x); s[1] = (short)f2bf(a0.y);
        s[2] = (short)f2bf(a0.z); s[3] = (short)f2bf(a0.w);
        s[4] = (short)f2bf(a1.x); s[5] = (short)f2bf(a1.y);
        s[6] = (short)f2bf(a1.z); s[7] = (short)f2bf(a1.w);
        afrag[kb] = s;
    }
    pd0 += __shfl_xor(pd0, 16); pd0 += __shfl_xor(pd0, 32);
    pd1 += __shfl_xor(pd1, 16); pd1 += __shfl_xor(pd1, 32);
    if (l < 16 && m0 + lr < n) *(float2*)(a_d + (size_t)(m0 + lr) * 2) = make_float2(pd0, pd1);

    f32x4 acc[8] = {};
    #pragma unroll
    for (int nt = 0; nt < 8; ++nt) {
        #pragma unroll
        for (int kb = 0; kb < 4; ++kb) {
            short8 b = *(const short8*)(Wt + (size_t)(nt * 16 + lr) * 128 + kb * 32 + quad * 8);
            acc[nt] = __builtin_amdgcn_mfma_f32_16x16x32_bf16(afrag[kb], b, acc[nt], 0, 0, 0);
        }
    }
    float asv[8];
    #pragma unroll
    for (int nt = 0; nt < 8; ++nt) asv[nt] = att_s[nt * 16 + lr];
    float pa0[4] = {}, pa1[4] = {};
    #pragma unroll
    for (int nt = 0; nt < 8; ++nt)
        #pragma unroll
        for (int r = 0; r < 4; ++r) {
            if (nt < 4) pa0[r] += acc[nt][r] * asv[nt];
            else        pa1[r] += acc[nt][r] * asv[nt];
        }
    #pragma unroll
    for (int d = 1; d < 16; d <<= 1) {
        #pragma unroll
        for (int r = 0; r < 4; ++r) {
            pa0[r] += __shfl_xor(pa0[r], d);
            pa1[r] += __shfl_xor(pa1[r], d);
        }
    }
    if (lr == 0) {
        #pragma unroll
        for (int r = 0; r < 4; ++r) {
            int row = m0 + quad * 4 + r;
            if (row < n) *(float2*)(a_s + (size_t)row * 2) = make_float2(pa0[r], pa1[r]);
        }
    }
    #pragma unroll
    for (int nt = 0; nt < 8; ++nt)
        #pragma unroll
        for (int r = 0; r < 4; ++r) {
            int row = m0 + quad * 4 + r;
            if (row < n)
                C[(size_t)row * 128 + nt * 16 + lr] = (unsigned short)f2bf(acc[nt][r]);
        }
}

__global__ __launch_bounds__(256) void gemm_fused_bf16_kernel(
    const unsigned short* __restrict__ A, const unsigned short* __restrict__ Wt,
    const float* __restrict__ att_s, const float* __restrict__ weffd,
    unsigned short* __restrict__ C, float* __restrict__ a_s, float* __restrict__ a_d, int n) {
    int t = threadIdx.x;
    int l = t & 63;
    int quad = l >> 4, lr = l & 15;
    int m0 = blockIdx.x * 64 + (t >> 6) * 16;
    int arow = m0 + lr; if (arow >= n) arow = n - 1;

    short8 afrag[4];
    float pd0 = 0.f, pd1 = 0.f;
    const float2* wd2 = (const float2*)weffd;
    #pragma unroll
    for (int kb = 0; kb < 4; ++kb) {
        short8 s = *(const short8*)(A + (size_t)arow * 128 + kb * 32 + quad * 8);
        afrag[kb] = s;
        const unsigned int* u = (const unsigned int*)&s;
        int k0 = kb * 32 + quad * 8;
        #pragma unroll
        for (int d = 0; d < 4; ++d) {
            float x0 = __uint_as_float(u[d] << 16);
            float x1 = __uint_as_float(u[d] & 0xffff0000u);
            float2 wv0 = wd2[k0 + 2*d], wv1 = wd2[k0 + 2*d + 1];
            pd0 += x0 * wv0.x + x1 * wv1.x;
            pd1 += x0 * wv0.y + x1 * wv1.y;
        }
    }
    pd0 += __shfl_xor(pd0, 16); pd0 += __shfl_xor(pd0, 32);
    pd1 += __shfl_xor(pd1, 16); pd1 += __shfl_xor(pd1, 32);
    if (l < 16 && m0 + lr < n) *(float2*)(a_d + (size_t)(m0 + lr) * 2) = make_float2(pd0, pd1);

    f32x4 acc[8] = {};
    #pragma unroll
    for (int nt = 0; nt < 8; ++nt) {
        #pragma unroll
        for (int kb = 0; kb < 4; ++kb) {
            short8 b = *(const short8*)(Wt + (size_t)(nt * 16 + lr) * 128 + kb * 32 + quad * 8);
            acc[nt] = __builtin_amdgcn_mfma_f32_16x16x32_bf16(afrag[kb], b, acc[nt], 0, 0, 0);
        }
    }
    float asv[8];
    #pragma unroll
    for (int nt = 0; nt < 8; ++nt) asv[nt] = att_s[nt * 16 + lr];
    float pa0[4] = {}, pa1[4] = {};
    #pragma unroll
    for (int nt = 0; nt < 8; ++nt)
        #pragma unroll
        for (int r = 0; r < 4; ++r) {
            if (nt < 4) pa0[r] += acc[nt][r] * asv[nt];
            else        pa1[r] += acc[nt][r] * asv[nt];
        }
    #pragma unroll
    for (int d = 1; d < 16; d <<= 1) {
        #pragma unroll
        for (int r = 0; r < 4; ++r) {
            pa0[r] += __shfl_xor(pa0[r], d);
            pa1[r] += __shfl_xor(pa1[r], d);
        }
    }
    if (lr == 0) {
        #pragma unroll
        for (int r = 0; r < 4; ++r) {
            int row = m0 + quad * 4 + r;
            if (row < n) *(float2*)(a_s + (size_t)row * 2) = make_float2(pa0[r], pa1[r]);
        }
    }
    #pragma unroll
    for (int nt = 0; nt < 8; ++nt)
        #pragma unroll
        for (int r = 0; r < 4; ++r) {
            int row = m0 + quad * 4 + r;
            if (row < n)
                C[(size_t)row * 128 + nt * 16 + lr] = (unsigned short)f2bf(acc[nt][r]);
        }
}

// ---------------- edge aggregation: one wave per TWO destination nodes ----------------
// Two independent gather streams per wave (interleaved 4-edge groups) -> 2x memory-level
// parallelism + halved per-wave fixed overhead. Lanes 0-31 head0 exp, 32-63 head1.

#define AGG_GRP(EIV, PME, X0, X1, Y0, Y1, JB)                                   \
    {                                                                           \
        _Pragma("unroll")                                                       \
        for (int u = 0; u < 4; ++u) {                                           \
            int j = (JB) + u;                                                   \
            int srcn = __shfl((EIV), j);                                        \
            float pj = __shfl((PME), j + hoff);                                 \
            unsigned int v = xs32[(size_t)srcn * 64 + lane];                    \
            float v0 = __uint_as_float(v << 16);                                \
            float v1 = __uint_as_float(v & 0xffff0000u);                        \
            if (u & 1) { Y0 += pj * v0; Y1 += pj * v1; }                        \
            else       { X0 += pj * v0; X1 += pj * v1; }                        \
        }                                                                       \
    }

__global__ __launch_bounds__(256) void aggregate_kernel(
    const int2* __restrict__ rsre, const unsigned short* __restrict__ eids,
    const float* __restrict__ a_s, const float* __restrict__ a_d,
    const unsigned int* __restrict__ xs32, const float* __restrict__ bias,
    unsigned int* __restrict__ out32, int npairs) {
    int wv = (int)((blockIdx.x * blockDim.x + threadIdx.x) >> 6);
    int lane = threadIdx.x & 63;
    if (wv >= npairs) return;
    int d0 = wv * 2, d1 = d0 + 1;          // N_NODES even -> d1 always valid
    int h = lane >> 5, j32 = lane & 31, hoff = h << 5, ch = lane * 2;
    float2 adp0 = *(const float2*)(a_d + (size_t)d0 * 2);
    float2 adp1 = *(const float2*)(a_d + (size_t)d1 * 2);
    float adv0 = (h == 0) ? adp0.x : adp0.y;
    float adv1 = (h == 0) ? adp1.x : adp1.y;
    int2 r0 = rsre[d0], r1 = rsre[d1];
    int b0 = r0.x, e0 = r0.y, b1 = r1.x, e1 = r1.y;

    float xA0 = 0, xA1 = 0, yA0 = 0, yA1 = 0;   // dst0
    float xB0 = 0, xB1 = 0, yB0 = 0, yB1 = 0;   // dst1
    float ls0 = 0, ls1 = 0;
    while (b0 < e0 || b1 < e1) {
        int k0 = e0 - b0; k0 = k0 < 0 ? 0 : (k0 > 32 ? 32 : k0);
        int k1 = e1 - b1; k1 = k1 < 0 ? 0 : (k1 > 32 ? 32 : k1);
        int ei0 = 0, ei1 = 0;
        float pm0 = 0.f, pm1 = 0.f;
        if (k0 > 0) {
            ei0 = (int)eids[b0 + (j32 < k0 ? j32 : k0 - 1)];
            float2 as2 = *(const float2*)(a_s + (size_t)ei0 * 2);
            float ev = ((h == 0) ? as2.x : as2.y) + adv0;
            ev = (ev > 0.f) ? ev : 0.2f * ev;
            pm0 = (j32 < k0) ? __expf(ev) : 0.f;
            ls0 += pm0;
        }
        if (k1 > 0) {
            ei1 = (int)eids[b1 + (j32 < k1 ? j32 : k1 - 1)];
            float2 as2 = *(const float2*)(a_s + (size_t)ei1 * 2);
            float ev = ((h == 0) ? as2.x : as2.y) + adv1;
            ev = (ev > 0.f) ? ev : 0.2f * ev;
            pm1 = (j32 < k1) ? __expf(ev) : 0.f;
            ls1 += pm1;
        }
        int jb0 = 0, jb1 = 0;
        while (jb0 + 4 <= k0 && jb1 + 4 <= k1) {      // interleaved: 2 indep streams
            AGG_GRP(ei0, pm0, xA0, xA1, yA0, yA1, jb0)
            AGG_GRP(ei1, pm1, xB0, xB1, yB0, yB1, jb1)
            jb0 += 4; jb1 += 4;
        }
        for (; jb0 + 4 <= k0; jb0 += 4) AGG_GRP(ei0, pm0, xA0, xA1, yA0, yA1, jb0)
        for (; jb1 + 4 <= k1; jb1 += 4) AGG_GRP(ei1, pm1, xB0, xB1, yB0, yB1, jb1)
        for (; jb0 < k0; ++jb0) {
            int srcn = __shfl(ei0, jb0);
            float pj = __shfl(pm0, jb0 + hoff);
            unsigned int v = xs32[(size_t)srcn * 64 + lane];
            xA0 += pj * __uint_as_float(v << 16);
            xA1 += pj * __uint_as_float(v & 0xffff0000u);
        }
        for (; jb1 < k1; ++jb1) {
            int srcn = __shfl(ei1, jb1);
            float pj = __shfl(pm1, jb1 + hoff);
            unsigned int v = xs32[(size_t)srcn * 64 + lane];
            xB0 += pj * __uint_as_float(v << 16);
            xB1 += pj * __uint_as_float(v & 0xffff0000u);
        }
        b0 += k0; b1 += k1;
    }
    #pragma unroll
    for (int d = 1; d <= 16; d <<= 1) {
        ls0 += __shfl_xor(ls0, d);
        ls1 += __shfl_xor(ls1, d);
    }
    float inv0 = 1.f / ls0, inv1 = 1.f / ls1;
    float bc0 = bias[ch], bc1 = bias[ch + 1];
    float o00 = fmaxf((xA0 + yA0) * inv0 + bc0, 0.f);
    float o01 = fmaxf((xA1 + yA1) * inv0 + bc1, 0.f);
    float o10 = fmaxf((xB0 + yB0) * inv1 + bc0, 0.f);
    float o11 = fmaxf((xB1 + yB1) * inv1 + bc1, 0.f);
    out32[(size_t)d0 * 64 + lane] = f2bf(o00) | (f2bf(o01) << 16);
    out32[(size_t)d1 * 64 + lane] = f2bf(o10) | (f2bf(o11) << 16);
}

// ---------------- pool + final linear fused (completion-counter) ----------------

__global__ __launch_bounds__(256) void pool_final_kernel(
    const unsigned short* __restrict__ Hf, const int* __restrict__ batch,
    const float* __restrict__ Wl, const float* __restrict__ bl,
    float* __restrict__ sums, int* __restrict__ counter,
    float* __restrict__ out, int n) {
    int t = threadIdx.x;
    int c = t & 127, half = t >> 7;
    int start = blockIdx.x * POOL_CHUNK;
    int end = min(start + POOL_CHUNK, n);
    float acc = 0.f;
    int cur = -1;
    for (int i = start + half; i < end; i += 2) {
        int g = batch[i];
        if (g != cur) {
            if (cur >= 0) atomicAdd(&sums[cur * 128 + c], acc);
            acc = 0.f; cur = g;
        }
        acc += bf2f(Hf[(size_t)i * 128 + c]);
    }
    if (cur >= 0) atomicAdd(&sums[cur * 128 + c], acc);
    __threadfence();
    __shared__ int lastFlag;
    if (t == 0) lastFlag = (atomicAdd(counter, 1) == (int)gridDim.x - 1);
    __syncthreads();
    if (!lastFlag) return;
    __threadfence();
    for (int q = t; q < N_GRAPHS * OUT_DIM; q += 256) {
        int g = q / OUT_DIM, o = q % OUT_DIM;
        int lo = 0, hi = n;
        while (lo < hi) { int mid = (lo + hi) >> 1; if (batch[mid] < g) lo = mid + 1; else hi = mid; }
        int s0 = lo; hi = n;
        while (lo < hi) { int mid = (lo + hi) >> 1; if (batch[mid] < g + 1) lo = mid + 1; else hi = mid; }
        float cnt = (float)(lo - s0);
        float inv = 1.f / fmaxf(cnt, 1.f);
        float s = bl[o];
        for (int cc = 0; cc < 128; ++cc) s += sums[g * 128 + cc] * inv * Wl[cc * OUT_DIM + o];
        out[q] = s;
    }
}

// ---------------- launch ----------------

extern "C" void kernel_launch(void* const* d_in, const int* in_sizes, int n_in,
                              void* d_out, int out_size, void* d_ws, size_t ws_size,
                              hipStream_t stream) {
    const float* x    = (const float*)d_in[0];
    const int*   ei   = (const int*)d_in[1];
    const int*   batch= (const int*)d_in[2];
    const float* Ws1  = (const float*)d_in[3];
    const float* Wd1  = (const float*)d_in[4];
    const float* as1  = (const float*)d_in[5];
    const float* ad1  = (const float*)d_in[6];
    const float* b1   = (const float*)d_in[7];
    const float* Ws2  = (const float*)d_in[8];
    const float* Wd2  = (const float*)d_in[9];
    const float* as2  = (const float*)d_in[10];
    const float* ad2  = (const float*)d_in[11];
    const float* b2   = (const float*)d_in[12];
    const float* Wl   = (const float*)d_in[13];
    const float* bl   = (const float*)d_in[14];
    float* out = (float*)d_out;

    char* p = (char*)d_ws;
    auto alloc = [&](size_t bytes) {
        void* r = (void*)p;
        p += (bytes + 255) & ~(size_t)255;
        return r;
    };
    int* bcursor  = (int*)alloc(sizeof(int) * NREP * NB);
    unsigned short* eids = (unsigned short*)alloc(sizeof(short) * (size_t)NB * EIDS_CAP);
    int2* rsre    = (int2*)alloc(sizeof(int2) * N_NODES);
    float* a_s    = (float*)alloc(sizeof(float) * N_NODES * 2);
    float* a_d    = (float*)alloc(sizeof(float) * N_NODES * 2);
    float* sums   = (float*)alloc(sizeof(float) * (N_GRAPHS * 128 + 64)); // sums + counter, one zero region (2064 uint4)
    int* counter  = (int*)(sums + N_GRAPHS * 128);
    float* weffd1 = (float*)alloc(sizeof(float) * 128 * 2);
    float* weffd2 = (float*)alloc(sizeof(float) * 128 * 2);
    unsigned short* Wt1  = (unsigned short*)alloc(sizeof(short) * 128 * 128);
    unsigned short* Wt2  = (unsigned short*)alloc(sizeof(short) * 128 * 128);
    unsigned short* bufA = (unsigned short*)alloc(sizeof(short) * (size_t)N_NODES * F_DIM);
    unsigned short* bufB = (unsigned short*)alloc(sizeof(short) * (size_t)N_NODES * F_DIM);
    // recs (NB*NREP*SUBCAP*4 = 4.6 MB) aliases bufA: dead before gemm1 writes bufA.
    unsigned int* recs = (unsigned int*)bufA;

    // ---- prep + CSR build ----
    prep_kernel<<<128, 256, 0, stream>>>(Ws1, Ws2, Wd1, ad1, Wd2, ad2,
                                         Wt1, Wt2, weffd1, weffd2,
                                         (uint4*)bcursor, (uint4*)sums);
    scatter_kernel<<<SC_BLOCKS, 1024, 0, stream>>>(ei, bcursor, recs);
    bucketize_kernel<<<NB, 256, 0, stream>>>(recs, bcursor, eids, rsre, N_NODES);

    const int gemm_grid = (N_NODES + 63) / 64;
    const int npairs    = N_NODES / 2;                    // 25000 (N even)
    const int agg_grid  = (npairs + 3) / 4;               // 4 waves/block

    // ---- layer 1 ----
    gemm_fused_f32a_kernel<<<gemm_grid, 256, 0, stream>>>(x, Wt1, as1, weffd1,
                                                          bufA, a_s, a_d, N_NODES);
    aggregate_kernel<<<agg_grid, 256, 0, stream>>>(rsre, eids, a_s, a_d,
                                                   (const unsigned int*)bufA, b1,
                                                   (unsigned int*)bufB, npairs);

    // ---- layer 2 ----
    gemm_fused_bf16_kernel<<<gemm_grid, 256, 0, stream>>>(bufB, Wt2, as2, weffd2,
                                                          bufA, a_s, a_d, N_NODES);
    aggregate_kernel<<<agg_grid, 256, 0, stream>>>(rsre, eids, a_s, a_d,
                                                   (const unsigned int*)bufA, b2,
                                                   (unsigned int*)bufB, npairs);

    // ---- pool + linear (fused) ----
    pool_final_kernel<<<POOL_BLOCKS, 256, 0, stream>>>(bufB, batch, Wl, bl,
                                                       sums, counter, out, N_NODES);
}

// Round 14
// 275.224 us; speedup vs baseline: 1.1522x; 1.1522x over previous
//
#include <hip/hip_runtime.h>
#include <hip/hip_bf16.h>

#define N_NODES 50000
#define N_EDGES 800000
#define EP (N_EDGES + N_NODES)
#define N_GRAPHS 64
#define F_DIM 128
#define OUT_DIM 10
#define NB 391                   // dst buckets of 128
#define NREP 8                   // cursor replicas: rep = blockIdx & 7
#define SUBCAP 384               // per (bucket,rep): E=256, +8 sigma
#define EIDS_CAP 2560            // per-bucket: E=2174 (incl selfloops), +8.6 sigma
#define SC_EDGES 4096            // edges per scatter block
#define SC_BLOCKS ((N_EDGES + SC_EDGES - 1) / SC_EDGES)   // 196
#define POOL_CHUNK 128
#define POOL_BLOCKS ((N_NODES + POOL_CHUNK - 1) / POOL_CHUNK) // 391

typedef __attribute__((ext_vector_type(8))) short short8;
typedef __attribute__((ext_vector_type(4))) float f32x4;

__device__ __forceinline__ unsigned int f2bf(float f) {
    unsigned int x; __builtin_memcpy(&x, &f, 4);
    return (x + 0x7fffu + ((x >> 16) & 1u)) >> 16;          // RNE
}
__device__ __forceinline__ float bf2f(unsigned int u16) {
    unsigned int x = u16 << 16;
    float f; __builtin_memcpy(&f, &x, 4); return f;
}

// ---------------- prep: zeros + W->Wt casts + weff_d ----------------

__global__ __launch_bounds__(256) void prep_kernel(
    const float* __restrict__ W1, const float* __restrict__ W2,
    const float* __restrict__ Wd1, const float* __restrict__ ad1,
    const float* __restrict__ Wd2, const float* __restrict__ ad2,
    unsigned short* __restrict__ Wt1, unsigned short* __restrict__ Wt2,
    float* __restrict__ weffd1, float* __restrict__ weffd2,
    uint4* __restrict__ zero_bcur /*782*/, uint4* __restrict__ zero_sums /*2048*/) {
    int tid = blockIdx.x * 256 + threadIdx.x;
    if (tid < 782) zero_bcur[tid] = make_uint4(0, 0, 0, 0);
    else if (tid < 782 + 2048) zero_sums[tid - 782] = make_uint4(0, 0, 0, 0);
    if (tid < 512) {
        const float* Wd = (tid < 256) ? Wd1 : Wd2;
        const float* ad = (tid < 256) ? ad1 : ad2;
        float* wout = (tid < 256) ? weffd1 : weffd2;
        int i = tid & 255, f = i >> 1, h = i & 1;
        const float4* wr = (const float4*)(Wd + f * 128 + h * 64);
        const float4* av = (const float4*)(ad + h * 64);
        float s = 0.f;
        #pragma unroll
        for (int c = 0; c < 16; ++c) {
            float4 w = wr[c], a = av[c];
            s += w.x*a.x + w.y*a.y + w.z*a.z + w.w*a.w;
        }
        wout[f * 2 + h] = s;
    }
    const float* W = (tid < 16384) ? W1 : W2;
    unsigned short* Wt = (tid < 16384) ? Wt1 : Wt2;
    int i = tid & 16383;
    int k = i >> 7, nn = i & 127;
    Wt[nn * 128 + k] = (unsigned short)f2bf(W[i]);
}

// ---------------- CSR build: LDS counting-sort scatter (coalesced run writes) ----------------

__global__ __launch_bounds__(1024) void scatter_kernel(const int* __restrict__ ei,
                                                       int* __restrict__ bcursor,
                                                       unsigned int* __restrict__ recs) {
    __shared__ unsigned int srec[SC_EDGES];   // 16 KB
    __shared__ int hist[NB], lcur[NB], gpos[NB];
    __shared__ int excl[512];
    int t = threadIdx.x;
    int base = blockIdx.x * SC_EDGES;
    int rep = blockIdx.x & (NREP - 1);
    for (int i = t; i < NB; i += 1024) { hist[i] = 0; lcur[i] = 0; }
    __syncthreads();
    unsigned int rec_[4]; int have[4];
    #pragma unroll
    for (int j = 0; j < 4; ++j) {
        int i = base + j * 1024 + t;
        have[j] = (i < N_EDGES);
        if (have[j]) {
            int src = ei[i], dst = ei[N_EDGES + i];
            int b = dst >> 7;
            rec_[j] = ((unsigned)b << 23) | ((unsigned)(dst & 127) << 16) | (unsigned)src;
            atomicAdd(&hist[b], 1);
        }
    }
    __syncthreads();
    if (t < 512) excl[t] = (t < NB) ? hist[t] : 0;
    __syncthreads();
    for (int off = 1; off < 512; off <<= 1) {
        int v = 0;
        if (t < 512 && t >= off) v = excl[t - off];
        __syncthreads();
        if (t < 512) excl[t] += v;
        __syncthreads();
    }
    if (t < NB && hist[t] > 0) gpos[t] = atomicAdd(&bcursor[rep * NB + t], hist[t]);
    __syncthreads();
    #pragma unroll
    for (int j = 0; j < 4; ++j) {
        if (have[j]) {
            int b = rec_[j] >> 23;
            int pos = atomicAdd(&lcur[b], 1);
            srec[(excl[b] - hist[b]) + pos] = rec_[j];
        }
    }
    __syncthreads();
    int cnt = N_EDGES - base; if (cnt > SC_EDGES) cnt = SC_EDGES;
    for (int i = t; i < cnt; i += 1024) {
        unsigned int rec = srec[i];
        int b = rec >> 23;
        int gp = gpos[b] + (i - (excl[b] - hist[b]));
        if (gp < SUBCAP)
            recs[((size_t)b * NREP + rep) * SUBCAP + gp] = rec & 0x7fffffu;
    }
}

// one block per bucket: concat 8 sub-segments + inject self-loops -> eids + (start,end)
__global__ __launch_bounds__(256) void bucketize_kernel(
    const unsigned int* __restrict__ recs, const int* __restrict__ bcursor,
    unsigned short* __restrict__ eids, int2* __restrict__ rsre, int n) {
    __shared__ int ssub[NREP + 1];
    __shared__ int hist[128], excl[128], cur[128];
    __shared__ unsigned int srec[EIDS_CAP];
    int b = blockIdx.x, t = threadIdx.x;
    int nvalid = n - b * 128; if (nvalid > 128) nvalid = 128;
    if (t < 128) { hist[t] = 0; cur[t] = 0; }
    if (t == 0) {
        int run = 0; ssub[0] = 0;
        for (int r = 0; r < NREP; ++r) {
            int c = bcursor[r * NB + b]; if (c > SUBCAP) c = SUBCAP;
            run += c; ssub[r + 1] = run;
        }
    }
    __syncthreads();
    int total = ssub[NREP];
    int maxsc = EIDS_CAP - 128;
    if (total > maxsc) total = maxsc;
    const unsigned int* rb = recs + (size_t)b * NREP * SUBCAP;
    for (int i = t; i < total; i += 256) {
        int r = 0;
        while (ssub[r + 1] <= i) ++r;
        unsigned int rec = rb[r * SUBCAP + (i - ssub[r])];
        srec[i] = rec;
        atomicAdd(&hist[(rec >> 16) & 127], 1);
    }
    __syncthreads();
    if (t < nvalid) hist[t] += 1;                    // self loop
    __syncthreads();
    if (t < 128) excl[t] = hist[t];
    __syncthreads();
    for (int off = 1; off < 128; off <<= 1) {
        int v = 0;
        if (t < 128 && t >= off) v = excl[t - off];
        __syncthreads();
        if (t < 128) excl[t] += v;
        __syncthreads();
    }
    int base2 = b * EIDS_CAP;
    if (t < nvalid) {
        int st = excl[t] - hist[t];
        rsre[b * 128 + t] = make_int2(base2 + st, base2 + excl[t]);
        eids[base2 + st] = (unsigned short)(b * 128 + t);
        cur[t] = 1;
    }
    __syncthreads();
    for (int i = t; i < total; i += 256) {
        unsigned int rec = srec[i];
        int dl = (rec >> 16) & 127;
        int pos = atomicAdd(&cur[dl], 1);
        eids[base2 + (excl[dl] - hist[dl]) + pos] = (unsigned short)(rec & 0xffffu);
    }
}

// ---------------- fused MFMA GEMM + attention scalars ----------------

__global__ __launch_bounds__(256) void gemm_fused_f32a_kernel(
    const float* __restrict__ A, const unsigned short* __restrict__ Wt,
    const float* __restrict__ att_s, const float* __restrict__ weffd,
    unsigned short* __restrict__ C, float* __restrict__ a_s, float* __restrict__ a_d, int n) {
    int t = threadIdx.x;
    int l = t & 63;
    int quad = l >> 4, lr = l & 15;
    int m0 = blockIdx.x * 64 + (t >> 6) * 16;
    int arow = m0 + lr; if (arow >= n) arow = n - 1;

    short8 afrag[4];
    float pd0 = 0.f, pd1 = 0.f;
    const float2* wd2 = (const float2*)weffd;
    #pragma unroll
    for (int kb = 0; kb < 4; ++kb) {
        const float4* ap = (const float4*)(A + (size_t)arow * 128 + kb * 32 + quad * 8);
        float4 a0 = ap[0], a1 = ap[1];
        int k0 = kb * 32 + quad * 8;
        float2 w0 = wd2[k0+0], w1 = wd2[k0+1], w2 = wd2[k0+2], w3 = wd2[k0+3];
        float2 w4 = wd2[k0+4], w5 = wd2[k0+5], w6 = wd2[k0+6], w7 = wd2[k0+7];
        pd0 += a0.x*w0.x + a0.y*w1.x + a0.z*w2.x + a0.w*w3.x
             + a1.x*w4.x + a1.y*w5.x + a1.z*w6.x + a1.w*w7.x;
        pd1 += a0.x*w0.y + a0.y*w1.y + a0.z*w2.y + a0.w*w3.y
             + a1.x*w4.y + a1.y*w5.y + a1.z*w6.y + a1.w*w7.y;
        short8 s;
        s[0] = (short)f2bf(a0.x); s[1] = (short)f2bf(a0.y);
        s[2] = (short)f2bf(a0.z); s[3] = (short)f2bf(a0.w);
        s[4] = (short)f2bf(a1.x); s[5] = (short)f2bf(a1.y);
        s[6] = (short)f2bf(a1.z); s[7] = (short)f2bf(a1.w);
        afrag[kb] = s;
    }
    pd0 += __shfl_xor(pd0, 16); pd0 += __shfl_xor(pd0, 32);
    pd1 += __shfl_xor(pd1, 16); pd1 += __shfl_xor(pd1, 32);
    if (l < 16 && m0 + lr < n) *(float2*)(a_d + (size_t)(m0 + lr) * 2) = make_float2(pd0, pd1);

    f32x4 acc[8] = {};
    #pragma unroll
    for (int nt = 0; nt < 8; ++nt) {
        #pragma unroll
        for (int kb = 0; kb < 4; ++kb) {
            short8 b = *(const short8*)(Wt + (size_t)(nt * 16 + lr) * 128 + kb * 32 + quad * 8);
            acc[nt] = __builtin_amdgcn_mfma_f32_16x16x32_bf16(afrag[kb], b, acc[nt], 0, 0, 0);
        }
    }
    float asv[8];
    #pragma unroll
    for (int nt = 0; nt < 8; ++nt) asv[nt] = att_s[nt * 16 + lr];
    float pa0[4] = {}, pa1[4] = {};
    #pragma unroll
    for (int nt = 0; nt < 8; ++nt)
        #pragma unroll
        for (int r = 0; r < 4; ++r) {
            if (nt < 4) pa0[r] += acc[nt][r] * asv[nt];
            else        pa1[r] += acc[nt][r] * asv[nt];
        }
    #pragma unroll
    for (int d = 1; d < 16; d <<= 1) {
        #pragma unroll
        for (int r = 0; r < 4; ++r) {
            pa0[r] += __shfl_xor(pa0[r], d);
            pa1[r] += __shfl_xor(pa1[r], d);
        }
    }
    if (lr == 0) {
        #pragma unroll
        for (int r = 0; r < 4; ++r) {
            int row = m0 + quad * 4 + r;
            if (row < n) *(float2*)(a_s + (size_t)row * 2) = make_float2(pa0[r], pa1[r]);
        }
    }
    #pragma unroll
    for (int nt = 0; nt < 8; ++nt)
        #pragma unroll
        for (int r = 0; r < 4; ++r) {
            int row = m0 + quad * 4 + r;
            if (row < n)
                C[(size_t)row * 128 + nt * 16 + lr] = (unsigned short)f2bf(acc[nt][r]);
        }
}

__global__ __launch_bounds__(256) void gemm_fused_bf16_kernel(
    const unsigned short* __restrict__ A, const unsigned short* __restrict__ Wt,
    const float* __restrict__ att_s, const float* __restrict__ weffd,
    unsigned short* __restrict__ C, float* __restrict__ a_s, float* __restrict__ a_d, int n) {
    int t = threadIdx.x;
    int l = t & 63;
    int quad = l >> 4, lr = l & 15;
    int m0 = blockIdx.x * 64 + (t >> 6) * 16;
    int arow = m0 + lr; if (arow >= n) arow = n - 1;

    short8 afrag[4];
    float pd0 = 0.f, pd1 = 0.f;
    const float2* wd2 = (const float2*)weffd;
    #pragma unroll
    for (int kb = 0; kb < 4; ++kb) {
        short8 s = *(const short8*)(A + (size_t)arow * 128 + kb * 32 + quad * 8);
        afrag[kb] = s;
        const unsigned int* u = (const unsigned int*)&s;
        int k0 = kb * 32 + quad * 8;
        #pragma unroll
        for (int d = 0; d < 4; ++d) {
            float x0 = __uint_as_float(u[d] << 16);
            float x1 = __uint_as_float(u[d] & 0xffff0000u);
            float2 wv0 = wd2[k0 + 2*d], wv1 = wd2[k0 + 2*d + 1];
            pd0 += x0 * wv0.x + x1 * wv1.x;
            pd1 += x0 * wv0.y + x1 * wv1.y;
        }
    }
    pd0 += __shfl_xor(pd0, 16); pd0 += __shfl_xor(pd0, 32);
    pd1 += __shfl_xor(pd1, 16); pd1 += __shfl_xor(pd1, 32);
    if (l < 16 && m0 + lr < n) *(float2*)(a_d + (size_t)(m0 + lr) * 2) = make_float2(pd0, pd1);

    f32x4 acc[8] = {};
    #pragma unroll
    for (int nt = 0; nt < 8; ++nt) {
        #pragma unroll
        for (int kb = 0; kb < 4; ++kb) {
            short8 b = *(const short8*)(Wt + (size_t)(nt * 16 + lr) * 128 + kb * 32 + quad * 8);
            acc[nt] = __builtin_amdgcn_mfma_f32_16x16x32_bf16(afrag[kb], b, acc[nt], 0, 0, 0);
        }
    }
    float asv[8];
    #pragma unroll
    for (int nt = 0; nt < 8; ++nt) asv[nt] = att_s[nt * 16 + lr];
    float pa0[4] = {}, pa1[4] = {};
    #pragma unroll
    for (int nt = 0; nt < 8; ++nt)
        #pragma unroll
        for (int r = 0; r < 4; ++r) {
            if (nt < 4) pa0[r] += acc[nt][r] * asv[nt];
            else        pa1[r] += acc[nt][r] * asv[nt];
        }
    #pragma unroll
    for (int d = 1; d < 16; d <<= 1) {
        #pragma unroll
        for (int r = 0; r < 4; ++r) {
            pa0[r] += __shfl_xor(pa0[r], d);
            pa1[r] += __shfl_xor(pa1[r], d);
        }
    }
    if (lr == 0) {
        #pragma unroll
        for (int r = 0; r < 4; ++r) {
            int row = m0 + quad * 4 + r;
            if (row < n) *(float2*)(a_s + (size_t)row * 2) = make_float2(pa0[r], pa1[r]);
        }
    }
    #pragma unroll
    for (int nt = 0; nt < 8; ++nt)
        #pragma unroll
        for (int r = 0; r < 4; ++r) {
            int row = m0 + quad * 4 + r;
            if (row < n)
                C[(size_t)row * 128 + nt * 16 + lr] = (unsigned short)f2bf(acc[nt][r]);
        }
}

// ---------------- edge aggregation: one wave per TWO destination nodes ----------------
// Two independent gather streams per wave (interleaved 4-edge groups) -> 2x memory-level
// parallelism + halved per-wave fixed overhead. Lanes 0-31 head0 exp, 32-63 head1.

#define AGG_GRP(EIV, PME, X0, X1, Y0, Y1, JB)                                   \
    {                                                                           \
        _Pragma("unroll")                                                       \
        for (int u = 0; u < 4; ++u) {                                           \
            int j = (JB) + u;                                                   \
            int srcn = __shfl((EIV), j);                                        \
            float pj = __shfl((PME), j + hoff);                                 \
            unsigned int v = xs32[(size_t)srcn * 64 + lane];                    \
            float v0 = __uint_as_float(v << 16);                                \
            float v1 = __uint_as_float(v & 0xffff0000u);                        \
            if (u & 1) { Y0 += pj * v0; Y1 += pj * v1; }                        \
            else       { X0 += pj * v0; X1 += pj * v1; }                        \
        }                                                                       \
    }

__global__ __launch_bounds__(256) void aggregate_kernel(
    const int2* __restrict__ rsre, const unsigned short* __restrict__ eids,
    const float* __restrict__ a_s, const float* __restrict__ a_d,
    const unsigned int* __restrict__ xs32, const float* __restrict__ bias,
    unsigned int* __restrict__ out32, int npairs) {
    int wv = (int)((blockIdx.x * blockDim.x + threadIdx.x) >> 6);
    int lane = threadIdx.x & 63;
    if (wv >= npairs) return;
    int d0 = wv * 2, d1 = d0 + 1;          // N_NODES even -> d1 always valid
    int h = lane >> 5, j32 = lane & 31, hoff = h << 5, ch = lane * 2;
    float2 adp0 = *(const float2*)(a_d + (size_t)d0 * 2);
    float2 adp1 = *(const float2*)(a_d + (size_t)d1 * 2);
    float adv0 = (h == 0) ? adp0.x : adp0.y;
    float adv1 = (h == 0) ? adp1.x : adp1.y;
    int2 r0 = rsre[d0], r1 = rsre[d1];
    int b0 = r0.x, e0 = r0.y, b1 = r1.x, e1 = r1.y;

    float xA0 = 0, xA1 = 0, yA0 = 0, yA1 = 0;   // dst0
    float xB0 = 0, xB1 = 0, yB0 = 0, yB1 = 0;   // dst1
    float ls0 = 0, ls1 = 0;
    while (b0 < e0 || b1 < e1) {
        int k0 = e0 - b0; k0 = k0 < 0 ? 0 : (k0 > 32 ? 32 : k0);
        int k1 = e1 - b1; k1 = k1 < 0 ? 0 : (k1 > 32 ? 32 : k1);
        int ei0 = 0, ei1 = 0;
        float pm0 = 0.f, pm1 = 0.f;
        if (k0 > 0) {
            ei0 = (int)eids[b0 + (j32 < k0 ? j32 : k0 - 1)];
            float2 as2 = *(const float2*)(a_s + (size_t)ei0 * 2);
            float ev = ((h == 0) ? as2.x : as2.y) + adv0;
            ev = (ev > 0.f) ? ev : 0.2f * ev;
            pm0 = (j32 < k0) ? __expf(ev) : 0.f;
            ls0 += pm0;
        }
        if (k1 > 0) {
            ei1 = (int)eids[b1 + (j32 < k1 ? j32 : k1 - 1)];
            float2 as2 = *(const float2*)(a_s + (size_t)ei1 * 2);
            float ev = ((h == 0) ? as2.x : as2.y) + adv1;
            ev = (ev > 0.f) ? ev : 0.2f * ev;
            pm1 = (j32 < k1) ? __expf(ev) : 0.f;
            ls1 += pm1;
        }
        int jb0 = 0, jb1 = 0;
        while (jb0 + 4 <= k0 && jb1 + 4 <= k1) {      // interleaved: 2 indep streams
            AGG_GRP(ei0, pm0, xA0, xA1, yA0, yA1, jb0)
            AGG_GRP(ei1, pm1, xB0, xB1, yB0, yB1, jb1)
            jb0 += 4; jb1 += 4;
        }
        for (; jb0 + 4 <= k0; jb0 += 4) AGG_GRP(ei0, pm0, xA0, xA1, yA0, yA1, jb0)
        for (; jb1 + 4 <= k1; jb1 += 4) AGG_GRP(ei1, pm1, xB0, xB1, yB0, yB1, jb1)
        for (; jb0 < k0; ++jb0) {
            int srcn = __shfl(ei0, jb0);
            float pj = __shfl(pm0, jb0 + hoff);
            unsigned int v = xs32[(size_t)srcn * 64 + lane];
            xA0 += pj * __uint_as_float(v << 16);
            xA1 += pj * __uint_as_float(v & 0xffff0000u);
        }
        for (; jb1 < k1; ++jb1) {
            int srcn = __shfl(ei1, jb1);
            float pj = __shfl(pm1, jb1 + hoff);
            unsigned int v = xs32[(size_t)srcn * 64 + lane];
            xB0 += pj * __uint_as_float(v << 16);
            xB1 += pj * __uint_as_float(v & 0xffff0000u);
        }
        b0 += k0; b1 += k1;
    }
    #pragma unroll
    for (int d = 1; d <= 16; d <<= 1) {
        ls0 += __shfl_xor(ls0, d);
        ls1 += __shfl_xor(ls1, d);
    }
    float inv0 = 1.f / ls0, inv1 = 1.f / ls1;
    float bc0 = bias[ch], bc1 = bias[ch + 1];
    float o00 = fmaxf((xA0 + yA0) * inv0 + bc0, 0.f);
    float o01 = fmaxf((xA1 + yA1) * inv0 + bc1, 0.f);
    float o10 = fmaxf((xB0 + yB0) * inv1 + bc0, 0.f);
    float o11 = fmaxf((xB1 + yB1) * inv1 + bc1, 0.f);
    out32[(size_t)d0 * 64 + lane] = f2bf(o00) | (f2bf(o01) << 16);
    out32[(size_t)d1 * 64 + lane] = f2bf(o10) | (f2bf(o11) << 16);
}

// ---------------- pool: partial sums + tiny final linear (separate kernels; no fences) ----------------

__global__ __launch_bounds__(256) void pool_partial_kernel(
    const unsigned short* __restrict__ Hf, const int* __restrict__ batch,
    float* __restrict__ sums, int n) {
    int t = threadIdx.x;
    int c = t & 127, half = t >> 7;
    int start = blockIdx.x * POOL_CHUNK;
    int end = min(start + POOL_CHUNK, n);
    float acc = 0.f;
    int cur = -1;
    for (int i = start + half; i < end; i += 2) {
        int g = batch[i];
        if (g != cur) {
            if (cur >= 0) atomicAdd(&sums[cur * 128 + c], acc);
            acc = 0.f; cur = g;
        }
        acc += bf2f(Hf[(size_t)i * 128 + c]);
    }
    if (cur >= 0) atomicAdd(&sums[cur * 128 + c], acc);
}

__global__ void final_linear_kernel(const float* __restrict__ sums,
                                    const int* __restrict__ batch,
                                    const float* __restrict__ Wl, const float* __restrict__ bl,
                                    float* __restrict__ out, int n) {
    int t = blockIdx.x * blockDim.x + threadIdx.x;
    if (t >= N_GRAPHS * OUT_DIM) return;
    int g = t / OUT_DIM, o = t % OUT_DIM;
    int lo = 0, hi = n;
    while (lo < hi) { int mid = (lo + hi) >> 1; if (batch[mid] < g) lo = mid + 1; else hi = mid; }
    int s0 = lo; hi = n;
    while (lo < hi) { int mid = (lo + hi) >> 1; if (batch[mid] < g + 1) lo = mid + 1; else hi = mid; }
    float cnt = (float)(lo - s0);
    float inv = 1.f / fmaxf(cnt, 1.f);
    float s = bl[o];
    for (int c = 0; c < 128; ++c) s += sums[g * 128 + c] * inv * Wl[c * OUT_DIM + o];
    out[g * OUT_DIM + o] = s;
}

// ---------------- launch ----------------

extern "C" void kernel_launch(void* const* d_in, const int* in_sizes, int n_in,
                              void* d_out, int out_size, void* d_ws, size_t ws_size,
                              hipStream_t stream) {
    const float* x    = (const float*)d_in[0];
    const int*   ei   = (const int*)d_in[1];
    const int*   batch= (const int*)d_in[2];
    const float* Ws1  = (const float*)d_in[3];
    const float* Wd1  = (const float*)d_in[4];
    const float* as1  = (const float*)d_in[5];
    const float* ad1  = (const float*)d_in[6];
    const float* b1   = (const float*)d_in[7];
    const float* Ws2  = (const float*)d_in[8];
    const float* Wd2  = (const float*)d_in[9];
    const float* as2  = (const float*)d_in[10];
    const float* ad2  = (const float*)d_in[11];
    const float* b2   = (const float*)d_in[12];
    const float* Wl   = (const float*)d_in[13];
    const float* bl   = (const float*)d_in[14];
    float* out = (float*)d_out;

    char* p = (char*)d_ws;
    auto alloc = [&](size_t bytes) {
        void* r = (void*)p;
        p += (bytes + 255) & ~(size_t)255;
        return r;
    };
    int* bcursor  = (int*)alloc(sizeof(int) * NREP * NB);
    unsigned short* eids = (unsigned short*)alloc(sizeof(short) * (size_t)NB * EIDS_CAP);
    int2* rsre    = (int2*)alloc(sizeof(int2) * N_NODES);
    float* a_s    = (float*)alloc(sizeof(float) * N_NODES * 2);
    float* a_d    = (float*)alloc(sizeof(float) * N_NODES * 2);
    float* sums   = (float*)alloc(sizeof(float) * N_GRAPHS * 128);
    float* weffd1 = (float*)alloc(sizeof(float) * 128 * 2);
    float* weffd2 = (float*)alloc(sizeof(float) * 128 * 2);
    unsigned short* Wt1  = (unsigned short*)alloc(sizeof(short) * 128 * 128);
    unsigned short* Wt2  = (unsigned short*)alloc(sizeof(short) * 128 * 128);
    unsigned short* bufA = (unsigned short*)alloc(sizeof(short) * (size_t)N_NODES * F_DIM);
    unsigned short* bufB = (unsigned short*)alloc(sizeof(short) * (size_t)N_NODES * F_DIM);
    // recs (NB*NREP*SUBCAP*4 = 4.6 MB) aliases bufA: dead before gemm1 writes bufA.
    unsigned int* recs = (unsigned int*)bufA;

    // ---- prep + CSR build ----
    prep_kernel<<<128, 256, 0, stream>>>(Ws1, Ws2, Wd1, ad1, Wd2, ad2,
                                         Wt1, Wt2, weffd1, weffd2,
                                         (uint4*)bcursor, (uint4*)sums);
    scatter_kernel<<<SC_BLOCKS, 1024, 0, stream>>>(ei, bcursor, recs);
    bucketize_kernel<<<NB, 256, 0, stream>>>(recs, bcursor, eids, rsre, N_NODES);

    const int gemm_grid = (N_NODES + 63) / 64;
    const int npairs    = N_NODES / 2;                    // 25000 (N even)
    const int agg_grid  = (npairs + 3) / 4;               // 4 waves/block

    // ---- layer 1 ----
    gemm_fused_f32a_kernel<<<gemm_grid, 256, 0, stream>>>(x, Wt1, as1, weffd1,
                                                          bufA, a_s, a_d, N_NODES);
    aggregate_kernel<<<agg_grid, 256, 0, stream>>>(rsre, eids, a_s, a_d,
                                                   (const unsigned int*)bufA, b1,
                                                   (unsigned int*)bufB, npairs);

    // ---- layer 2 ----
    gemm_fused_bf16_kernel<<<gemm_grid, 256, 0, stream>>>(bufB, Wt2, as2, weffd2,
                                                          bufA, a_s, a_d, N_NODES);
    aggregate_kernel<<<agg_grid, 256, 0, stream>>>(rsre, eids, a_s, a_d,
                                                   (const unsigned int*)bufA, b2,
                                                   (unsigned int*)bufB, npairs);

    // ---- pool + linear ----
    pool_partial_kernel<<<POOL_BLOCKS, 256, 0, stream>>>(bufB, batch, sums, N_NODES);
    final_linear_kernel<<<(N_GRAPHS * OUT_DIM + 255) / 256, 256, 0, stream>>>(sums, batch, Wl, bl, out, N_NODES);
}

// Round 15
// 265.515 us; speedup vs baseline: 1.1943x; 1.0366x over previous
//
#include <hip/hip_runtime.h>
#include <hip/hip_bf16.h>

#define N_NODES 50000
#define N_EDGES 800000
#define N_GRAPHS 64
#define F_DIM 128
#define OUT_DIM 10
#define NB 391                   // dst buckets of 128
#define EIDS_CAP 2560            // per-bucket: E=2174 (incl selfloops), +8.6 sigma
#define SC_EDGES 4096            // edges per scatter block (its private region size)
#define SC_BLOCKS ((N_EDGES + SC_EDGES - 1) / SC_EDGES)   // 196
#define POOL_CHUNK 128
#define POOL_BLOCKS ((N_NODES + POOL_CHUNK - 1) / POOL_CHUNK) // 391

typedef __attribute__((ext_vector_type(8))) short short8;
typedef __attribute__((ext_vector_type(4))) float f32x4;

__device__ __forceinline__ unsigned int f2bf(float f) {
    unsigned int x; __builtin_memcpy(&x, &f, 4);
    return (x + 0x7fffu + ((x >> 16) & 1u)) >> 16;          // RNE
}
__device__ __forceinline__ float bf2f(unsigned int u16) {
    unsigned int x = u16 << 16;
    float f; __builtin_memcpy(&f, &x, 4); return f;
}

// ---------------- scatter + prep fused ----------------
// Per-block-region counting sort: block blk sorts its 4096 edges by bucket into
// recs[blk*4096 ..] (contiguous copy, coalesced) and writes its inclusive per-bucket
// scan to exclT[blk*NB + b]. NO global atomics, NO pre-zeroed state.
// Prep work (W casts, weffd, sums zero) distributed over global tids.

__global__ __launch_bounds__(1024) void scatter_prep_kernel(
    const int* __restrict__ ei,
    const float* __restrict__ W1, const float* __restrict__ W2,
    const float* __restrict__ Wd1, const float* __restrict__ ad1,
    const float* __restrict__ Wd2, const float* __restrict__ ad2,
    unsigned short* __restrict__ Wt1, unsigned short* __restrict__ Wt2,
    float* __restrict__ weffd1, float* __restrict__ weffd2,
    uint4* __restrict__ zero_sums /*2048*/,
    unsigned int* __restrict__ recs, int* __restrict__ exclT) {
    __shared__ unsigned int srec[SC_EDGES];   // 16 KB
    __shared__ int hist[NB], lcur[NB];
    __shared__ int excl[512];
    int t = threadIdx.x;
    int blk = blockIdx.x;
    int tid = blk * 1024 + t;

    // ---- prep (independent, spread over first blocks) ----
    if (tid < 32768) {
        const float* W = (tid < 16384) ? W1 : W2;
        unsigned short* Wt = (tid < 16384) ? Wt1 : Wt2;
        int i = tid & 16383;
        int k = i >> 7, nn = i & 127;
        Wt[nn * 128 + k] = (unsigned short)f2bf(W[i]);
    } else if (tid < 33280) {
        int j = tid - 32768;                 // 0..511
        const float* Wd = (j < 256) ? Wd1 : Wd2;
        const float* ad = (j < 256) ? ad1 : ad2;
        float* wout = (j < 256) ? weffd1 : weffd2;
        int i = j & 255, f = i >> 1, h = i & 1;
        const float4* wr = (const float4*)(Wd + f * 128 + h * 64);
        const float4* av = (const float4*)(ad + h * 64);
        float s = 0.f;
        #pragma unroll
        for (int c = 0; c < 16; ++c) {
            float4 w = wr[c], a = av[c];
            s += w.x*a.x + w.y*a.y + w.z*a.z + w.w*a.w;
        }
        wout[f * 2 + h] = s;
    } else if (tid < 35328) {
        zero_sums[tid - 33280] = make_uint4(0, 0, 0, 0);
    }

    // ---- per-block counting sort ----
    int base = blk * SC_EDGES;
    for (int i = t; i < NB; i += 1024) { hist[i] = 0; lcur[i] = 0; }
    __syncthreads();
    unsigned int rec_[4]; int have[4];
    #pragma unroll
    for (int j = 0; j < 4; ++j) {
        int i = base + j * 1024 + t;
        have[j] = (i < N_EDGES);
        if (have[j]) {
            int src = ei[i], dst = ei[N_EDGES + i];
            int b = dst >> 7;
            rec_[j] = ((unsigned)b << 23) | ((unsigned)(dst & 127) << 16) | (unsigned)src;
            atomicAdd(&hist[b], 1);
        }
    }
    __syncthreads();
    if (t < 512) excl[t] = (t < NB) ? hist[t] : 0;
    __syncthreads();
    for (int off = 1; off < 512; off <<= 1) {        // inclusive scan over buckets
        int v = 0;
        if (t < 512 && t >= off) v = excl[t - off];
        __syncthreads();
        if (t < 512) excl[t] += v;
        __syncthreads();
    }
    #pragma unroll
    for (int j = 0; j < 4; ++j) {
        if (have[j]) {
            int b = rec_[j] >> 23;
            int pos = atomicAdd(&lcur[b], 1);
            srec[(excl[b] - hist[b]) + pos] = rec_[j];
        }
    }
    __syncthreads();
    int cnt = N_EDGES - base; if (cnt > SC_EDGES) cnt = SC_EDGES;
    for (int i = t; i < cnt; i += 1024)              // contiguous coalesced copy
        recs[(size_t)blk * SC_EDGES + i] = srec[i];
    if (t < NB) exclT[blk * NB + t] = excl[t];       // coalesced run-table write
}

// ---------------- gemm1 (f32 A) + bucketize fused ----------------
// Blocks < NB rebuild bucket b's CSR (concat 196 region runs + self-loops);
// ALL blocks do the layer-1 GEMM + attention scalars. Independent work.

__global__ __launch_bounds__(256) void gemm1_bucketize_kernel(
    const float* __restrict__ A, const unsigned short* __restrict__ Wt,
    const float* __restrict__ att_s, const float* __restrict__ weffd,
    const unsigned int* __restrict__ recs, const int* __restrict__ exclT,
    unsigned short* __restrict__ C, float* __restrict__ a_s, float* __restrict__ a_d,
    unsigned short* __restrict__ eids, int2* __restrict__ rsre, int n) {
    __shared__ unsigned int srec[EIDS_CAP];          // 10 KB
    __shared__ int lo0[SC_BLOCKS], cntb[SC_BLOCKS];
    __shared__ int sc[256];
    __shared__ int pexcl[SC_BLOCKS + 1];
    __shared__ int hist[128], excl[128], cur[128];
    int t = threadIdx.x;

    if (blockIdx.x < NB) {
        int b = blockIdx.x;
        int nvalid = n - b * 128; if (nvalid > 128) nvalid = 128;
        if (t < 128) { hist[t] = 0; cur[t] = 0; }
        for (int i = t; i < SC_BLOCKS; i += 256) {
            int hi = exclT[i * NB + b];
            int l  = b ? exclT[i * NB + b - 1] : 0;
            lo0[i] = l; cntb[i] = hi - l;
        }
        __syncthreads();
        sc[t] = (t < SC_BLOCKS) ? cntb[t] : 0;
        __syncthreads();
        for (int off = 1; off < 256; off <<= 1) {    // inclusive scan over regions
            int v = (t >= off) ? sc[t - off] : 0;
            __syncthreads();
            sc[t] += v;
            __syncthreads();
        }
        if (t < SC_BLOCKS) pexcl[t] = sc[t] - cntb[t];
        if (t == 0) pexcl[SC_BLOCKS] = sc[255];
        __syncthreads();
        int total = pexcl[SC_BLOCKS];
        int maxsc = EIDS_CAP - 128;
        if (total > maxsc) total = maxsc;
        for (int i = t; i < total; i += 256) {
            int l = 0, h = SC_BLOCKS;                // largest l with pexcl[l] <= i
            while (l + 1 < h) { int m = (l + h) >> 1; if (pexcl[m] <= i) l = m; else h = m; }
            unsigned int rec = recs[(size_t)l * SC_EDGES + lo0[l] + (i - pexcl[l])];
            srec[i] = rec;
            atomicAdd(&hist[(rec >> 16) & 127], 1);
        }
        __syncthreads();
        if (t < nvalid) hist[t] += 1;                // self loop
        __syncthreads();
        if (t < 128) excl[t] = hist[t];
        __syncthreads();
        for (int off = 1; off < 128; off <<= 1) {
            int v = 0;
            if (t < 128 && t >= off) v = excl[t - off];
            __syncthreads();
            if (t < 128) excl[t] += v;
            __syncthreads();
        }
        int base2 = b * EIDS_CAP;
        if (t < nvalid) {
            int st = excl[t] - hist[t];
            rsre[b * 128 + t] = make_int2(base2 + st, base2 + excl[t]);
            eids[base2 + st] = (unsigned short)(b * 128 + t);   // self-loop first
            cur[t] = 1;
        }
        __syncthreads();
        for (int i = t; i < total; i += 256) {
            unsigned int rec = srec[i];
            int dl = (rec >> 16) & 127;
            int pos = atomicAdd(&cur[dl], 1);
            eids[base2 + (excl[dl] - hist[dl]) + pos] = (unsigned short)(rec & 0xffffu);
        }
    }

    // ---- gemm part (all blocks) ----
    int l = t & 63;
    int quad = l >> 4, lr = l & 15;
    int m0 = blockIdx.x * 64 + (t >> 6) * 16;
    int arow = m0 + lr; if (arow >= n) arow = n - 1;

    short8 afrag[4];
    float pd0 = 0.f, pd1 = 0.f;
    const float2* wd2 = (const float2*)weffd;
    #pragma unroll
    for (int kb = 0; kb < 4; ++kb) {
        const float4* ap = (const float4*)(A + (size_t)arow * 128 + kb * 32 + quad * 8);
        float4 a0 = ap[0], a1 = ap[1];
        int k0 = kb * 32 + quad * 8;
        float2 w0 = wd2[k0+0], w1 = wd2[k0+1], w2 = wd2[k0+2], w3 = wd2[k0+3];
        float2 w4 = wd2[k0+4], w5 = wd2[k0+5], w6 = wd2[k0+6], w7 = wd2[k0+7];
        pd0 += a0.x*w0.x + a0.y*w1.x + a0.z*w2.x + a0.w*w3.x
             + a1.x*w4.x + a1.y*w5.x + a1.z*w6.x + a1.w*w7.x;
        pd1 += a0.x*w0.y + a0.y*w1.y + a0.z*w2.y + a0.w*w3.y
             + a1.x*w4.y + a1.y*w5.y + a1.z*w6.y + a1.w*w7.y;
        short8 s;
        s[0] = (short)f2bf(a0.x); s[1] = (short)f2bf(a0.y);
        s[2] = (short)f2bf(a0.z); s[3] = (short)f2bf(a0.w);
        s[4] = (short)f2bf(a1.x); s[5] = (short)f2bf(a1.y);
        s[6] = (short)f2bf(a1.z); s[7] = (short)f2bf(a1.w);
        afrag[kb] = s;
    }
    pd0 += __shfl_xor(pd0, 16); pd0 += __shfl_xor(pd0, 32);
    pd1 += __shfl_xor(pd1, 16); pd1 += __shfl_xor(pd1, 32);
    if (l < 16 && m0 + lr < n) *(float2*)(a_d + (size_t)(m0 + lr) * 2) = make_float2(pd0, pd1);

    f32x4 acc[8] = {};
    #pragma unroll
    for (int nt = 0; nt < 8; ++nt) {
        #pragma unroll
        for (int kb = 0; kb < 4; ++kb) {
            short8 b = *(const short8*)(Wt + (size_t)(nt * 16 + lr) * 128 + kb * 32 + quad * 8);
            acc[nt] = __builtin_amdgcn_mfma_f32_16x16x32_bf16(afrag[kb], b, acc[nt], 0, 0, 0);
        }
    }
    float asv[8];
    #pragma unroll
    for (int nt = 0; nt < 8; ++nt) asv[nt] = att_s[nt * 16 + lr];
    float pa0[4] = {}, pa1[4] = {};
    #pragma unroll
    for (int nt = 0; nt < 8; ++nt)
        #pragma unroll
        for (int r = 0; r < 4; ++r) {
            if (nt < 4) pa0[r] += acc[nt][r] * asv[nt];
            else        pa1[r] += acc[nt][r] * asv[nt];
        }
    #pragma unroll
    for (int d = 1; d < 16; d <<= 1) {
        #pragma unroll
        for (int r = 0; r < 4; ++r) {
            pa0[r] += __shfl_xor(pa0[r], d);
            pa1[r] += __shfl_xor(pa1[r], d);
        }
    }
    if (lr == 0) {
        #pragma unroll
        for (int r = 0; r < 4; ++r) {
            int row = m0 + quad * 4 + r;
            if (row < n) *(float2*)(a_s + (size_t)row * 2) = make_float2(pa0[r], pa1[r]);
        }
    }
    #pragma unroll
    for (int nt = 0; nt < 8; ++nt)
        #pragma unroll
        for (int r = 0; r < 4; ++r) {
            int row = m0 + quad * 4 + r;
            if (row < n)
                C[(size_t)row * 128 + nt * 16 + lr] = (unsigned short)f2bf(acc[nt][r]);
        }
}

// ---------------- gemm (bf16 A, layer 2) ----------------

__global__ __launch_bounds__(256) void gemm_fused_bf16_kernel(
    const unsigned short* __restrict__ A, const unsigned short* __restrict__ Wt,
    const float* __restrict__ att_s, const float* __restrict__ weffd,
    unsigned short* __restrict__ C, float* __restrict__ a_s, float* __restrict__ a_d, int n) {
    int t = threadIdx.x;
    int l = t & 63;
    int quad = l >> 4, lr = l & 15;
    int m0 = blockIdx.x * 64 + (t >> 6) * 16;
    int arow = m0 + lr; if (arow >= n) arow = n - 1;

    short8 afrag[4];
    float pd0 = 0.f, pd1 = 0.f;
    const float2* wd2 = (const float2*)weffd;
    #pragma unroll
    for (int kb = 0; kb < 4; ++kb) {
        short8 s = *(const short8*)(A + (size_t)arow * 128 + kb * 32 + quad * 8);
        afrag[kb] = s;
        const unsigned int* u = (const unsigned int*)&s;
        int k0 = kb * 32 + quad * 8;
        #pragma unroll
        for (int d = 0; d < 4; ++d) {
            float x0 = __uint_as_float(u[d] << 16);
            float x1 = __uint_as_float(u[d] & 0xffff0000u);
            float2 wv0 = wd2[k0 + 2*d], wv1 = wd2[k0 + 2*d + 1];
            pd0 += x0 * wv0.x + x1 * wv1.x;
            pd1 += x0 * wv0.y + x1 * wv1.y;
        }
    }
    pd0 += __shfl_xor(pd0, 16); pd0 += __shfl_xor(pd0, 32);
    pd1 += __shfl_xor(pd1, 16); pd1 += __shfl_xor(pd1, 32);
    if (l < 16 && m0 + lr < n) *(float2*)(a_d + (size_t)(m0 + lr) * 2) = make_float2(pd0, pd1);

    f32x4 acc[8] = {};
    #pragma unroll
    for (int nt = 0; nt < 8; ++nt) {
        #pragma unroll
        for (int kb = 0; kb < 4; ++kb) {
            short8 b = *(const short8*)(Wt + (size_t)(nt * 16 + lr) * 128 + kb * 32 + quad * 8);
            acc[nt] = __builtin_amdgcn_mfma_f32_16x16x32_bf16(afrag[kb], b, acc[nt], 0, 0, 0);
        }
    }
    float asv[8];
    #pragma unroll
    for (int nt = 0; nt < 8; ++nt) asv[nt] = att_s[nt * 16 + lr];
    float pa0[4] = {}, pa1[4] = {};
    #pragma unroll
    for (int nt = 0; nt < 8; ++nt)
        #pragma unroll
        for (int r = 0; r < 4; ++r) {
            if (nt < 4) pa0[r] += acc[nt][r] * asv[nt];
            else        pa1[r] += acc[nt][r] * asv[nt];
        }
    #pragma unroll
    for (int d = 1; d < 16; d <<= 1) {
        #pragma unroll
        for (int r = 0; r < 4; ++r) {
            pa0[r] += __shfl_xor(pa0[r], d);
            pa1[r] += __shfl_xor(pa1[r], d);
        }
    }
    if (lr == 0) {
        #pragma unroll
        for (int r = 0; r < 4; ++r) {
            int row = m0 + quad * 4 + r;
            if (row < n) *(float2*)(a_s + (size_t)row * 2) = make_float2(pa0[r], pa1[r]);
        }
    }
    #pragma unroll
    for (int nt = 0; nt < 8; ++nt)
        #pragma unroll
        for (int r = 0; r < 4; ++r) {
            int row = m0 + quad * 4 + r;
            if (row < n)
                C[(size_t)row * 128 + nt * 16 + lr] = (unsigned short)f2bf(acc[nt][r]);
        }
}

// ---------------- edge aggregation: one wave per TWO destination nodes ----------------

#define AGG_GRP(EIV, PME, X0, X1, Y0, Y1, JB)                                   \
    {                                                                           \
        _Pragma("unroll")                                                       \
        for (int u = 0; u < 4; ++u) {                                           \
            int j = (JB) + u;                                                   \
            int srcn = __shfl((EIV), j);                                        \
            float pj = __shfl((PME), j + hoff);                                 \
            unsigned int v = xs32[(size_t)srcn * 64 + lane];                    \
            float v0 = __uint_as_float(v << 16);                                \
            float v1 = __uint_as_float(v & 0xffff0000u);                        \
            if (u & 1) { Y0 += pj * v0; Y1 += pj * v1; }                        \
            else       { X0 += pj * v0; X1 += pj * v1; }                        \
        }                                                                       \
    }

__global__ __launch_bounds__(256) void aggregate_kernel(
    const int2* __restrict__ rsre, const unsigned short* __restrict__ eids,
    const float* __restrict__ a_s, const float* __restrict__ a_d,
    const unsigned int* __restrict__ xs32, const float* __restrict__ bias,
    unsigned int* __restrict__ out32, int npairs) {
    int wv = (int)((blockIdx.x * blockDim.x + threadIdx.x) >> 6);
    int lane = threadIdx.x & 63;
    if (wv >= npairs) return;
    int d0 = wv * 2, d1 = d0 + 1;
    int h = lane >> 5, j32 = lane & 31, hoff = h << 5, ch = lane * 2;
    float2 adp0 = *(const float2*)(a_d + (size_t)d0 * 2);
    float2 adp1 = *(const float2*)(a_d + (size_t)d1 * 2);
    float adv0 = (h == 0) ? adp0.x : adp0.y;
    float adv1 = (h == 0) ? adp1.x : adp1.y;
    int2 r0 = rsre[d0], r1 = rsre[d1];
    int b0 = r0.x, e0 = r0.y, b1 = r1.x, e1 = r1.y;

    float xA0 = 0, xA1 = 0, yA0 = 0, yA1 = 0;
    float xB0 = 0, xB1 = 0, yB0 = 0, yB1 = 0;
    float ls0 = 0, ls1 = 0;
    while (b0 < e0 || b1 < e1) {
        int k0 = e0 - b0; k0 = k0 < 0 ? 0 : (k0 > 32 ? 32 : k0);
        int k1 = e1 - b1; k1 = k1 < 0 ? 0 : (k1 > 32 ? 32 : k1);
        int ei0 = 0, ei1 = 0;
        float pm0 = 0.f, pm1 = 0.f;
        if (k0 > 0) {
            ei0 = (int)eids[b0 + (j32 < k0 ? j32 : k0 - 1)];
            float2 as2 = *(const float2*)(a_s + (size_t)ei0 * 2);
            float ev = ((h == 0) ? as2.x : as2.y) + adv0;
            ev = (ev > 0.f) ? ev : 0.2f * ev;
            pm0 = (j32 < k0) ? __expf(ev) : 0.f;
            ls0 += pm0;
        }
        if (k1 > 0) {
            ei1 = (int)eids[b1 + (j32 < k1 ? j32 : k1 - 1)];
            float2 as2 = *(const float2*)(a_s + (size_t)ei1 * 2);
            float ev = ((h == 0) ? as2.x : as2.y) + adv1;
            ev = (ev > 0.f) ? ev : 0.2f * ev;
            pm1 = (j32 < k1) ? __expf(ev) : 0.f;
            ls1 += pm1;
        }
        int jb0 = 0, jb1 = 0;
        while (jb0 + 4 <= k0 && jb1 + 4 <= k1) {
            AGG_GRP(ei0, pm0, xA0, xA1, yA0, yA1, jb0)
            AGG_GRP(ei1, pm1, xB0, xB1, yB0, yB1, jb1)
            jb0 += 4; jb1 += 4;
        }
        for (; jb0 + 4 <= k0; jb0 += 4) AGG_GRP(ei0, pm0, xA0, xA1, yA0, yA1, jb0)
        for (; jb1 + 4 <= k1; jb1 += 4) AGG_GRP(ei1, pm1, xB0, xB1, yB0, yB1, jb1)
        for (; jb0 < k0; ++jb0) {
            int srcn = __shfl(ei0, jb0);
            float pj = __shfl(pm0, jb0 + hoff);
            unsigned int v = xs32[(size_t)srcn * 64 + lane];
            xA0 += pj * __uint_as_float(v << 16);
            xA1 += pj * __uint_as_float(v & 0xffff0000u);
        }
        for (; jb1 < k1; ++jb1) {
            int srcn = __shfl(ei1, jb1);
            float pj = __shfl(pm1, jb1 + hoff);
            unsigned int v = xs32[(size_t)srcn * 64 + lane];
            xB0 += pj * __uint_as_float(v << 16);
            xB1 += pj * __uint_as_float(v & 0xffff0000u);
        }
        b0 += k0; b1 += k1;
    }
    #pragma unroll
    for (int d = 1; d <= 16; d <<= 1) {
        ls0 += __shfl_xor(ls0, d);
        ls1 += __shfl_xor(ls1, d);
    }
    float inv0 = 1.f / ls0, inv1 = 1.f / ls1;
    float bc0 = bias[ch], bc1 = bias[ch + 1];
    float o00 = fmaxf((xA0 + yA0) * inv0 + bc0, 0.f);
    float o01 = fmaxf((xA1 + yA1) * inv0 + bc1, 0.f);
    float o10 = fmaxf((xB0 + yB0) * inv1 + bc0, 0.f);
    float o11 = fmaxf((xB1 + yB1) * inv1 + bc1, 0.f);
    out32[(size_t)d0 * 64 + lane] = f2bf(o00) | (f2bf(o01) << 16);
    out32[(size_t)d1 * 64 + lane] = f2bf(o10) | (f2bf(o11) << 16);
}

// ---------------- pool: partial sums + tiny final linear ----------------

__global__ __launch_bounds__(256) void pool_partial_kernel(
    const unsigned short* __restrict__ Hf, const int* __restrict__ batch,
    float* __restrict__ sums, int n) {
    int t = threadIdx.x;
    int c = t & 127, half = t >> 7;
    int start = blockIdx.x * POOL_CHUNK;
    int end = min(start + POOL_CHUNK, n);
    float acc = 0.f;
    int cur = -1;
    for (int i = start + half; i < end; i += 2) {
        int g = batch[i];
        if (g != cur) {
            if (cur >= 0) atomicAdd(&sums[cur * 128 + c], acc);
            acc = 0.f; cur = g;
        }
        acc += bf2f(Hf[(size_t)i * 128 + c]);
    }
    if (cur >= 0) atomicAdd(&sums[cur * 128 + c], acc);
}

__global__ void final_linear_kernel(const float* __restrict__ sums,
                                    const int* __restrict__ batch,
                                    const float* __restrict__ Wl, const float* __restrict__ bl,
                                    float* __restrict__ out, int n) {
    int t = blockIdx.x * blockDim.x + threadIdx.x;
    if (t >= N_GRAPHS * OUT_DIM) return;
    int g = t / OUT_DIM, o = t % OUT_DIM;
    int lo = 0, hi = n;
    while (lo < hi) { int mid = (lo + hi) >> 1; if (batch[mid] < g) lo = mid + 1; else hi = mid; }
    int s0 = lo; hi = n;
    while (lo < hi) { int mid = (lo + hi) >> 1; if (batch[mid] < g + 1) lo = mid + 1; else hi = mid; }
    float cnt = (float)(lo - s0);
    float inv = 1.f / fmaxf(cnt, 1.f);
    float s = bl[o];
    for (int c = 0; c < 128; ++c) s += sums[g * 128 + c] * inv * Wl[c * OUT_DIM + o];
    out[g * OUT_DIM + o] = s;
}

// ---------------- launch ----------------

extern "C" void kernel_launch(void* const* d_in, const int* in_sizes, int n_in,
                              void* d_out, int out_size, void* d_ws, size_t ws_size,
                              hipStream_t stream) {
    const float* x    = (const float*)d_in[0];
    const int*   ei   = (const int*)d_in[1];
    const int*   batch= (const int*)d_in[2];
    const float* Ws1  = (const float*)d_in[3];
    const float* Wd1  = (const float*)d_in[4];
    const float* as1  = (const float*)d_in[5];
    const float* ad1  = (const float*)d_in[6];
    const float* b1   = (const float*)d_in[7];
    const float* Ws2  = (const float*)d_in[8];
    const float* Wd2  = (const float*)d_in[9];
    const float* as2  = (const float*)d_in[10];
    const float* ad2  = (const float*)d_in[11];
    const float* b2   = (const float*)d_in[12];
    const float* Wl   = (const float*)d_in[13];
    const float* bl   = (const float*)d_in[14];
    float* out = (float*)d_out;

    // ws_size ~256 MB (measured via harness fill WRITE_SIZE); we use ~33 MB.
    char* p = (char*)d_ws;
    auto alloc = [&](size_t bytes) {
        void* r = (void*)p;
        p += (bytes + 255) & ~(size_t)255;
        return r;
    };
    int* exclT    = (int*)alloc(sizeof(int) * SC_BLOCKS * NB);                 // 306 KB
    unsigned int* recs = (unsigned int*)alloc(sizeof(int) * (size_t)SC_BLOCKS * SC_EDGES); // 3.2 MB
    unsigned short* eids = (unsigned short*)alloc(sizeof(short) * (size_t)NB * EIDS_CAP);  // 2.0 MB
    int2* rsre    = (int2*)alloc(sizeof(int2) * N_NODES);
    float* a_s    = (float*)alloc(sizeof(float) * N_NODES * 2);
    float* a_d    = (float*)alloc(sizeof(float) * N_NODES * 2);
    float* sums   = (float*)alloc(sizeof(float) * N_GRAPHS * 128);
    float* weffd1 = (float*)alloc(sizeof(float) * 128 * 2);
    float* weffd2 = (float*)alloc(sizeof(float) * 128 * 2);
    unsigned short* Wt1  = (unsigned short*)alloc(sizeof(short) * 128 * 128);
    unsigned short* Wt2  = (unsigned short*)alloc(sizeof(short) * 128 * 128);
    unsigned short* bufA = (unsigned short*)alloc(sizeof(short) * (size_t)N_NODES * F_DIM);
    unsigned short* bufB = (unsigned short*)alloc(sizeof(short) * (size_t)N_NODES * F_DIM);

    const int gemm_grid = (N_NODES + 63) / 64;            // 782 (>= NB)
    const int npairs    = N_NODES / 2;
    const int agg_grid  = (npairs + 3) / 4;

    // ---- CSR build + prep (fused) ----
    scatter_prep_kernel<<<SC_BLOCKS, 1024, 0, stream>>>(ei, Ws1, Ws2, Wd1, ad1, Wd2, ad2,
                                                        Wt1, Wt2, weffd1, weffd2,
                                                        (uint4*)sums, recs, exclT);

    // ---- layer 1 (gemm + bucketize fused) ----
    gemm1_bucketize_kernel<<<gemm_grid, 256, 0, stream>>>(x, Wt1, as1, weffd1,
                                                          recs, exclT,
                                                          bufA, a_s, a_d,
                                                          eids, rsre, N_NODES);
    aggregate_kernel<<<agg_grid, 256, 0, stream>>>(rsre, eids, a_s, a_d,
                                                   (const unsigned int*)bufA, b1,
                                                   (unsigned int*)bufB, npairs);

    // ---- layer 2 ----
    gemm_fused_bf16_kernel<<<gemm_grid, 256, 0, stream>>>(bufB, Wt2, as2, weffd2,
                                                          bufA, a_s, a_d, N_NODES);
    aggregate_kernel<<<agg_grid, 256, 0, stream>>>(rsre, eids, a_s, a_d,
                                                   (const unsigned int*)bufA, b2,
                                                   (unsigned int*)bufB, npairs);

    // ---- pool + linear ----
    pool_partial_kernel<<<POOL_BLOCKS, 256, 0, stream>>>(bufB, batch, sums, N_NODES);
    final_linear_kernel<<<(N_GRAPHS * OUT_DIM + 255) / 256, 256, 0, stream>>>(sums, batch, Wl, bl, out, N_NODES);
}

// Round 16
// 265.509 us; speedup vs baseline: 1.1944x; 1.0000x over previous
//
#include <hip/hip_runtime.h>
#include <hip/hip_bf16.h>

#define N_NODES 50000
#define N_EDGES 800000
#define N_GRAPHS 64
#define F_DIM 128
#define OUT_DIM 10
#define NB2 782                  // dst buckets of 64 (one per gemm1 block)
#define NREG 392                 // scatter regions
#define SC_EDGES 2048            // edges per scatter region
#define EIDS_HALF 1408           // per-bucket eids cap: E=1088 (incl selfloops), +10 sigma
#define POOL_CHUNK 128
#define POOL_BLOCKS ((N_NODES + POOL_CHUNK - 1) / POOL_CHUNK) // 391

typedef __attribute__((ext_vector_type(8))) short short8;
typedef __attribute__((ext_vector_type(4))) float f32x4;

__device__ __forceinline__ unsigned int f2bf(float f) {
    unsigned int x; __builtin_memcpy(&x, &f, 4);
    return (x + 0x7fffu + ((x >> 16) & 1u)) >> 16;          // RNE
}
__device__ __forceinline__ float bf2f(unsigned int u16) {
    unsigned int x = u16 << 16;
    float f; __builtin_memcpy(&f, &x, 4); return f;
}

// ---------------- scatter + prep fused ----------------
// Region r (block) counting-sorts its 2048 edges into 782 bins; writes sorted recs
// to its private region recs[r*2048..] and the per-bin inclusive scan to exclT[r*NB2+b].
// No global atomics. Prep (W casts, weffd, sums zero) spread over global tids.

__global__ __launch_bounds__(1024) void scatter_prep_kernel(
    const int* __restrict__ ei,
    const float* __restrict__ W1, const float* __restrict__ W2,
    const float* __restrict__ Wd1, const float* __restrict__ ad1,
    const float* __restrict__ Wd2, const float* __restrict__ ad2,
    unsigned short* __restrict__ Wt1, unsigned short* __restrict__ Wt2,
    float* __restrict__ weffd1, float* __restrict__ weffd2,
    uint4* __restrict__ zero_sums /*2048*/,
    unsigned int* __restrict__ recs, int* __restrict__ exclT) {
    __shared__ unsigned int srec[SC_EDGES];   // 8 KB
    __shared__ int hist[NB2], lcur[NB2];      // 6.3 KB
    __shared__ int excl[1024];                // 4 KB
    int t = threadIdx.x;
    int blk = blockIdx.x;
    int tid = blk * 1024 + t;

    // ---- prep (independent work, first blocks) ----
    if (tid < 32768) {
        const float* W = (tid < 16384) ? W1 : W2;
        unsigned short* Wt = (tid < 16384) ? Wt1 : Wt2;
        int i = tid & 16383;
        int k = i >> 7, nn = i & 127;
        Wt[nn * 128 + k] = (unsigned short)f2bf(W[i]);
    } else if (tid < 33280) {
        int j = tid - 32768;                 // 0..511
        const float* Wd = (j < 256) ? Wd1 : Wd2;
        const float* ad = (j < 256) ? ad1 : ad2;
        float* wout = (j < 256) ? weffd1 : weffd2;
        int i = j & 255, f = i >> 1, h = i & 1;
        const float4* wr = (const float4*)(Wd + f * 128 + h * 64);
        const float4* av = (const float4*)(ad + h * 64);
        float s = 0.f;
        #pragma unroll
        for (int c = 0; c < 16; ++c) {
            float4 w = wr[c], a = av[c];
            s += w.x*a.x + w.y*a.y + w.z*a.z + w.w*a.w;
        }
        wout[f * 2 + h] = s;
    } else if (tid < 35328) {
        zero_sums[tid - 33280] = make_uint4(0, 0, 0, 0);
    }

    // ---- per-region counting sort ----
    int base = blk * SC_EDGES;
    for (int i = t; i < NB2; i += 1024) { hist[i] = 0; lcur[i] = 0; }
    __syncthreads();
    unsigned int rec_[2]; int have[2];
    #pragma unroll
    for (int j = 0; j < 2; ++j) {
        int i = base + j * 1024 + t;
        have[j] = (i < N_EDGES);
        if (have[j]) {
            int src = ei[i], dst = ei[N_EDGES + i];
            int b2 = dst >> 6;
            rec_[j] = ((unsigned)b2 << 22) | ((unsigned)(dst & 63) << 16) | (unsigned)src;
            atomicAdd(&hist[b2], 1);
        }
    }
    __syncthreads();
    excl[t] = (t < NB2) ? hist[t] : 0;
    __syncthreads();
    for (int off = 1; off < 1024; off <<= 1) {       // inclusive scan over 782 bins
        int v = (t >= off) ? excl[t - off] : 0;
        __syncthreads();
        excl[t] += v;
        __syncthreads();
    }
    #pragma unroll
    for (int j = 0; j < 2; ++j) {
        if (have[j]) {
            int b2 = rec_[j] >> 22;
            int pos = atomicAdd(&lcur[b2], 1);
            srec[(excl[b2] - hist[b2]) + pos] = rec_[j];
        }
    }
    __syncthreads();
    int cnt = N_EDGES - base; if (cnt > SC_EDGES) cnt = SC_EDGES;
    for (int i = t; i < cnt; i += 1024)              // contiguous coalesced copy
        recs[(size_t)blk * SC_EDGES + i] = srec[i];
    if (t < NB2) exclT[blk * NB2 + t] = excl[t];     // coalesced run-table write
}

// ---------------- gemm1 (f32 A) + bucketize fused ----------------
// Block j rebuilds bucket j's CSR (concat its 392 region runs + self-loops)
// AND does its 64-row tile of the layer-1 GEMM + attention scalars.

__global__ __launch_bounds__(256) void gemm1_bucketize_kernel(
    const float* __restrict__ A, const unsigned short* __restrict__ Wt,
    const float* __restrict__ att_s, const float* __restrict__ weffd,
    const unsigned int* __restrict__ recs, const int* __restrict__ exclT,
    unsigned short* __restrict__ C, float* __restrict__ a_s, float* __restrict__ a_d,
    unsigned short* __restrict__ eids, int2* __restrict__ rsre, int n) {
    __shared__ unsigned int srec[EIDS_HALF];         // 5.6 KB
    __shared__ int lo0[NREG], cntb[NREG];            // 3.1 KB
    __shared__ int sc[256];
    __shared__ int pexcl[NREG + 1];
    __shared__ int hist[64], excl[64], cur[64];
    int t = threadIdx.x;
    int b2 = blockIdx.x;                             // grid == NB2

    {
        int nvalid = n - b2 * 64; if (nvalid > 64) nvalid = 64; if (nvalid < 0) nvalid = 0;
        if (t < 64) { hist[t] = 0; cur[t] = 0; }
        for (int r = t; r < NREG; r += 256) {
            int hi = exclT[r * NB2 + b2];
            int l  = b2 ? exclT[r * NB2 + b2 - 1] : 0;
            lo0[r] = l; cntb[r] = hi - l;
        }
        __syncthreads();
        // pair-scan over 392 region counts with 256 threads
        int c0 = (2 * t < NREG) ? cntb[2 * t] : 0;
        int c1 = (2 * t + 1 < NREG) ? cntb[2 * t + 1] : 0;
        sc[t] = c0 + c1;
        __syncthreads();
        for (int off = 1; off < 256; off <<= 1) {
            int v = (t >= off) ? sc[t - off] : 0;
            __syncthreads();
            sc[t] += v;
            __syncthreads();
        }
        int ex = sc[t] - (c0 + c1);
        if (2 * t < NREG) pexcl[2 * t] = ex;
        if (2 * t + 1 < NREG) pexcl[2 * t + 1] = ex + c0;
        if (t == 255) pexcl[NREG] = sc[255];
        __syncthreads();
        int total = pexcl[NREG];
        int maxsc = EIDS_HALF - 64;
        if (total > maxsc) total = maxsc;
        for (int i = t; i < total; i += 256) {
            int l = 0, h = NREG;                     // largest l with pexcl[l] <= i
            while (l + 1 < h) { int m = (l + h) >> 1; if (pexcl[m] <= i) l = m; else h = m; }
            unsigned int rec = recs[(size_t)l * SC_EDGES + lo0[l] + (i - pexcl[l])];
            srec[i] = rec;
            atomicAdd(&hist[(rec >> 16) & 63], 1);
        }
        __syncthreads();
        if (t < nvalid) hist[t] += 1;                // self loop
        __syncthreads();
        if (t < 64) excl[t] = hist[t];
        __syncthreads();
        for (int off = 1; off < 64; off <<= 1) {
            int v = 0;
            if (t < 64 && t >= off) v = excl[t - off];
            __syncthreads();
            if (t < 64) excl[t] += v;
            __syncthreads();
        }
        int base2 = b2 * EIDS_HALF;
        if (t < nvalid) {
            int st = excl[t] - hist[t];
            rsre[b2 * 64 + t] = make_int2(base2 + st, base2 + excl[t]);
            eids[base2 + st] = (unsigned short)(b2 * 64 + t);   // self-loop first
            cur[t] = 1;
        }
        __syncthreads();
        for (int i = t; i < total; i += 256) {
            unsigned int rec = srec[i];
            int dl = (rec >> 16) & 63;
            int pos = atomicAdd(&cur[dl], 1);
            eids[base2 + (excl[dl] - hist[dl]) + pos] = (unsigned short)(rec & 0xffffu);
        }
    }

    // ---- gemm part ----
    int l = t & 63;
    int quad = l >> 4, lr = l & 15;
    int m0 = blockIdx.x * 64 + (t >> 6) * 16;
    int arow = m0 + lr; if (arow >= n) arow = n - 1;

    short8 afrag[4];
    float pd0 = 0.f, pd1 = 0.f;
    const float2* wd2 = (const float2*)weffd;
    #pragma unroll
    for (int kb = 0; kb < 4; ++kb) {
        const float4* ap = (const float4*)(A + (size_t)arow * 128 + kb * 32 + quad * 8);
        float4 a0 = ap[0], a1 = ap[1];
        int k0 = kb * 32 + quad * 8;
        float2 w0 = wd2[k0+0], w1 = wd2[k0+1], w2 = wd2[k0+2], w3 = wd2[k0+3];
        float2 w4 = wd2[k0+4], w5 = wd2[k0+5], w6 = wd2[k0+6], w7 = wd2[k0+7];
        pd0 += a0.x*w0.x + a0.y*w1.x + a0.z*w2.x + a0.w*w3.x
             + a1.x*w4.x + a1.y*w5.x + a1.z*w6.x + a1.w*w7.x;
        pd1 += a0.x*w0.y + a0.y*w1.y + a0.z*w2.y + a0.w*w3.y
             + a1.x*w4.y + a1.y*w5.y + a1.z*w6.y + a1.w*w7.y;
        short8 s;
        s[0] = (short)f2bf(a0.x); s[1] = (short)f2bf(a0.y);
        s[2] = (short)f2bf(a0.z); s[3] = (short)f2bf(a0.w);
        s[4] = (short)f2bf(a1.x); s[5] = (short)f2bf(a1.y);
        s[6] = (short)f2bf(a1.z); s[7] = (short)f2bf(a1.w);
        afrag[kb] = s;
    }
    pd0 += __shfl_xor(pd0, 16); pd0 += __shfl_xor(pd0, 32);
    pd1 += __shfl_xor(pd1, 16); pd1 += __shfl_xor(pd1, 32);
    if (l < 16 && m0 + lr < n) *(float2*)(a_d + (size_t)(m0 + lr) * 2) = make_float2(pd0, pd1);

    f32x4 acc[8] = {};
    #pragma unroll
    for (int nt = 0; nt < 8; ++nt) {
        #pragma unroll
        for (int kb = 0; kb < 4; ++kb) {
            short8 b = *(const short8*)(Wt + (size_t)(nt * 16 + lr) * 128 + kb * 32 + quad * 8);
            acc[nt] = __builtin_amdgcn_mfma_f32_16x16x32_bf16(afrag[kb], b, acc[nt], 0, 0, 0);
        }
    }
    float asv[8];
    #pragma unroll
    for (int nt = 0; nt < 8; ++nt) asv[nt] = att_s[nt * 16 + lr];
    float pa0[4] = {}, pa1[4] = {};
    #pragma unroll
    for (int nt = 0; nt < 8; ++nt)
        #pragma unroll
        for (int r = 0; r < 4; ++r) {
            if (nt < 4) pa0[r] += acc[nt][r] * asv[nt];
            else        pa1[r] += acc[nt][r] * asv[nt];
        }
    #pragma unroll
    for (int d = 1; d < 16; d <<= 1) {
        #pragma unroll
        for (int r = 0; r < 4; ++r) {
            pa0[r] += __shfl_xor(pa0[r], d);
            pa1[r] += __shfl_xor(pa1[r], d);
        }
    }
    if (lr == 0) {
        #pragma unroll
        for (int r = 0; r < 4; ++r) {
            int row = m0 + quad * 4 + r;
            if (row < n) *(float2*)(a_s + (size_t)row * 2) = make_float2(pa0[r], pa1[r]);
        }
    }
    #pragma unroll
    for (int nt = 0; nt < 8; ++nt)
        #pragma unroll
        for (int r = 0; r < 4; ++r) {
            int row = m0 + quad * 4 + r;
            if (row < n)
                C[(size_t)row * 128 + nt * 16 + lr] = (unsigned short)f2bf(acc[nt][r]);
        }
}

// ---------------- gemm (bf16 A, layer 2) ----------------

__global__ __launch_bounds__(256) void gemm_fused_bf16_kernel(
    const unsigned short* __restrict__ A, const unsigned short* __restrict__ Wt,
    const float* __restrict__ att_s, const float* __restrict__ weffd,
    unsigned short* __restrict__ C, float* __restrict__ a_s, float* __restrict__ a_d, int n) {
    int t = threadIdx.x;
    int l = t & 63;
    int quad = l >> 4, lr = l & 15;
    int m0 = blockIdx.x * 64 + (t >> 6) * 16;
    int arow = m0 + lr; if (arow >= n) arow = n - 1;

    short8 afrag[4];
    float pd0 = 0.f, pd1 = 0.f;
    const float2* wd2 = (const float2*)weffd;
    #pragma unroll
    for (int kb = 0; kb < 4; ++kb) {
        short8 s = *(const short8*)(A + (size_t)arow * 128 + kb * 32 + quad * 8);
        afrag[kb] = s;
        const unsigned int* u = (const unsigned int*)&s;
        int k0 = kb * 32 + quad * 8;
        #pragma unroll
        for (int d = 0; d < 4; ++d) {
            float x0 = __uint_as_float(u[d] << 16);
            float x1 = __uint_as_float(u[d] & 0xffff0000u);
            float2 wv0 = wd2[k0 + 2*d], wv1 = wd2[k0 + 2*d + 1];
            pd0 += x0 * wv0.x + x1 * wv1.x;
            pd1 += x0 * wv0.y + x1 * wv1.y;
        }
    }
    pd0 += __shfl_xor(pd0, 16); pd0 += __shfl_xor(pd0, 32);
    pd1 += __shfl_xor(pd1, 16); pd1 += __shfl_xor(pd1, 32);
    if (l < 16 && m0 + lr < n) *(float2*)(a_d + (size_t)(m0 + lr) * 2) = make_float2(pd0, pd1);

    f32x4 acc[8] = {};
    #pragma unroll
    for (int nt = 0; nt < 8; ++nt) {
        #pragma unroll
        for (int kb = 0; kb < 4; ++kb) {
            short8 b = *(const short8*)(Wt + (size_t)(nt * 16 + lr) * 128 + kb * 32 + quad * 8);
            acc[nt] = __builtin_amdgcn_mfma_f32_16x16x32_bf16(afrag[kb], b, acc[nt], 0, 0, 0);
        }
    }
    float asv[8];
    #pragma unroll
    for (int nt = 0; nt < 8; ++nt) asv[nt] = att_s[nt * 16 + lr];
    float pa0[4] = {}, pa1[4] = {};
    #pragma unroll
    for (int nt = 0; nt < 8; ++nt)
        #pragma unroll
        for (int r = 0; r < 4; ++r) {
            if (nt < 4) pa0[r] += acc[nt][r] * asv[nt];
            else        pa1[r] += acc[nt][r] * asv[nt];
        }
    #pragma unroll
    for (int d = 1; d < 16; d <<= 1) {
        #pragma unroll
        for (int r = 0; r < 4; ++r) {
            pa0[r] += __shfl_xor(pa0[r], d);
            pa1[r] += __shfl_xor(pa1[r], d);
        }
    }
    if (lr == 0) {
        #pragma unroll
        for (int r = 0; r < 4; ++r) {
            int row = m0 + quad * 4 + r;
            if (row < n) *(float2*)(a_s + (size_t)row * 2) = make_float2(pa0[r], pa1[r]);
        }
    }
    #pragma unroll
    for (int nt = 0; nt < 8; ++nt)
        #pragma unroll
        for (int r = 0; r < 4; ++r) {
            int row = m0 + quad * 4 + r;
            if (row < n)
                C[(size_t)row * 128 + nt * 16 + lr] = (unsigned short)f2bf(acc[nt][r]);
        }
}

// ---------------- edge aggregation: one wave per TWO destination nodes ----------------

#define AGG_GRP(EIV, PME, X0, X1, Y0, Y1, JB)                                   \
    {                                                                           \
        _Pragma("unroll")                                                       \
        for (int u = 0; u < 4; ++u) {                                           \
            int j = (JB) + u;                                                   \
            int srcn = __shfl((EIV), j);                                        \
            float pj = __shfl((PME), j + hoff);                                 \
            unsigned int v = xs32[(size_t)srcn * 64 + lane];                    \
            float v0 = __uint_as_float(v << 16);                                \
            float v1 = __uint_as_float(v & 0xffff0000u);                        \
            if (u & 1) { Y0 += pj * v0; Y1 += pj * v1; }                        \
            else       { X0 += pj * v0; X1 += pj * v1; }                        \
        }                                                                       \
    }

__global__ __launch_bounds__(256) void aggregate_kernel(
    const int2* __restrict__ rsre, const unsigned short* __restrict__ eids,
    const float* __restrict__ a_s, const float* __restrict__ a_d,
    const unsigned int* __restrict__ xs32, const float* __restrict__ bias,
    unsigned int* __restrict__ out32, int npairs) {
    int wv = (int)((blockIdx.x * blockDim.x + threadIdx.x) >> 6);
    int lane = threadIdx.x & 63;
    if (wv >= npairs) return;
    int d0 = wv * 2, d1 = d0 + 1;
    int h = lane >> 5, j32 = lane & 31, hoff = h << 5, ch = lane * 2;
    float2 adp0 = *(const float2*)(a_d + (size_t)d0 * 2);
    float2 adp1 = *(const float2*)(a_d + (size_t)d1 * 2);
    float adv0 = (h == 0) ? adp0.x : adp0.y;
    float adv1 = (h == 0) ? adp1.x : adp1.y;
    int2 r0 = rsre[d0], r1 = rsre[d1];
    int b0 = r0.x, e0 = r0.y, b1 = r1.x, e1 = r1.y;

    float xA0 = 0, xA1 = 0, yA0 = 0, yA1 = 0;
    float xB0 = 0, xB1 = 0, yB0 = 0, yB1 = 0;
    float ls0 = 0, ls1 = 0;
    while (b0 < e0 || b1 < e1) {
        int k0 = e0 - b0; k0 = k0 < 0 ? 0 : (k0 > 32 ? 32 : k0);
        int k1 = e1 - b1; k1 = k1 < 0 ? 0 : (k1 > 32 ? 32 : k1);
        int ei0 = 0, ei1 = 0;
        float pm0 = 0.f, pm1 = 0.f;
        if (k0 > 0) {
            ei0 = (int)eids[b0 + (j32 < k0 ? j32 : k0 - 1)];
            float2 as2 = *(const float2*)(a_s + (size_t)ei0 * 2);
            float ev = ((h == 0) ? as2.x : as2.y) + adv0;
            ev = (ev > 0.f) ? ev : 0.2f * ev;
            pm0 = (j32 < k0) ? __expf(ev) : 0.f;
            ls0 += pm0;
        }
        if (k1 > 0) {
            ei1 = (int)eids[b1 + (j32 < k1 ? j32 : k1 - 1)];
            float2 as2 = *(const float2*)(a_s + (size_t)ei1 * 2);
            float ev = ((h == 0) ? as2.x : as2.y) + adv1;
            ev = (ev > 0.f) ? ev : 0.2f * ev;
            pm1 = (j32 < k1) ? __expf(ev) : 0.f;
            ls1 += pm1;
        }
        int jb0 = 0, jb1 = 0;
        while (jb0 + 4 <= k0 && jb1 + 4 <= k1) {
            AGG_GRP(ei0, pm0, xA0, xA1, yA0, yA1, jb0)
            AGG_GRP(ei1, pm1, xB0, xB1, yB0, yB1, jb1)
            jb0 += 4; jb1 += 4;
        }
        for (; jb0 + 4 <= k0; jb0 += 4) AGG_GRP(ei0, pm0, xA0, xA1, yA0, yA1, jb0)
        for (; jb1 + 4 <= k1; jb1 += 4) AGG_GRP(ei1, pm1, xB0, xB1, yB0, yB1, jb1)
        for (; jb0 < k0; ++jb0) {
            int srcn = __shfl(ei0, jb0);
            float pj = __shfl(pm0, jb0 + hoff);
            unsigned int v = xs32[(size_t)srcn * 64 + lane];
            xA0 += pj * __uint_as_float(v << 16);
            xA1 += pj * __uint_as_float(v & 0xffff0000u);
        }
        for (; jb1 < k1; ++jb1) {
            int srcn = __shfl(ei1, jb1);
            float pj = __shfl(pm1, jb1 + hoff);
            unsigned int v = xs32[(size_t)srcn * 64 + lane];
            xB0 += pj * __uint_as_float(v << 16);
            xB1 += pj * __uint_as_float(v & 0xffff0000u);
        }
        b0 += k0; b1 += k1;
    }
    #pragma unroll
    for (int d = 1; d <= 16; d <<= 1) {
        ls0 += __shfl_xor(ls0, d);
        ls1 += __shfl_xor(ls1, d);
    }
    float inv0 = 1.f / ls0, inv1 = 1.f / ls1;
    float bc0 = bias[ch], bc1 = bias[ch + 1];
    float o00 = fmaxf((xA0 + yA0) * inv0 + bc0, 0.f);
    float o01 = fmaxf((xA1 + yA1) * inv0 + bc1, 0.f);
    float o10 = fmaxf((xB0 + yB0) * inv1 + bc0, 0.f);
    float o11 = fmaxf((xB1 + yB1) * inv1 + bc1, 0.f);
    out32[(size_t)d0 * 64 + lane] = f2bf(o00) | (f2bf(o01) << 16);
    out32[(size_t)d1 * 64 + lane] = f2bf(o10) | (f2bf(o11) << 16);
}

// ---------------- pool: vectorized loads + LDS-staged per-graph accumulation ----------------

__global__ __launch_bounds__(256) void pool_partial_kernel(
    const unsigned short* __restrict__ Hf, const int* __restrict__ batch,
    float* __restrict__ sums, int n) {
    __shared__ float acc2[2][128];
    __shared__ int sgf;
    int t = threadIdx.x;
    acc2[t >> 7][t & 127] = 0.f;
    int start = blockIdx.x * POOL_CHUNK;
    int end = min(start + POOL_CHUNK, n);
    if (t == 0) sgf = batch[start];
    __syncthreads();
    int gfirst = sgf;
    int c4 = (t & 31) * 4;                   // channels c4..c4+3
    int sub = t >> 5;                        // 0..7
    float a0 = 0, a1 = 0, a2 = 0, a3 = 0;
    int cur = -1;
    for (int i = start + sub; i < end; i += 8) {
        int g = batch[i];
        if (g != cur) {
            if (cur >= 0) {
                int idx = cur - gfirst;
                if (idx < 2) {
                    atomicAdd(&acc2[idx][c4+0], a0); atomicAdd(&acc2[idx][c4+1], a1);
                    atomicAdd(&acc2[idx][c4+2], a2); atomicAdd(&acc2[idx][c4+3], a3);
                } else {
                    atomicAdd(&sums[cur*128+c4+0], a0); atomicAdd(&sums[cur*128+c4+1], a1);
                    atomicAdd(&sums[cur*128+c4+2], a2); atomicAdd(&sums[cur*128+c4+3], a3);
                }
                a0 = a1 = a2 = a3 = 0.f;
            }
            cur = g;
        }
        uint2 v = *(const uint2*)(Hf + (size_t)i * 128 + c4);
        a0 += bf2f(v.x & 0xffffu); a1 += bf2f(v.x >> 16);
        a2 += bf2f(v.y & 0xffffu); a3 += bf2f(v.y >> 16);
    }
    if (cur >= 0) {
        int idx = cur - gfirst;
        if (idx < 2) {
            atomicAdd(&acc2[idx][c4+0], a0); atomicAdd(&acc2[idx][c4+1], a1);
            atomicAdd(&acc2[idx][c4+2], a2); atomicAdd(&acc2[idx][c4+3], a3);
        } else {
            atomicAdd(&sums[cur*128+c4+0], a0); atomicAdd(&sums[cur*128+c4+1], a1);
            atomicAdd(&sums[cur*128+c4+2], a2); atomicAdd(&sums[cur*128+c4+3], a3);
        }
    }
    __syncthreads();
    int g = gfirst + (t >> 7);
    float v = acc2[t >> 7][t & 127];
    if (g < N_GRAPHS && v != 0.f) atomicAdd(&sums[g * 128 + (t & 127)], v);
}

__global__ void final_linear_kernel(const float* __restrict__ sums,
                                    const int* __restrict__ batch,
                                    const float* __restrict__ Wl, const float* __restrict__ bl,
                                    float* __restrict__ out, int n) {
    int t = blockIdx.x * blockDim.x + threadIdx.x;
    if (t >= N_GRAPHS * OUT_DIM) return;
    int g = t / OUT_DIM, o = t % OUT_DIM;
    int lo = 0, hi = n;
    while (lo < hi) { int mid = (lo + hi) >> 1; if (batch[mid] < g) lo = mid + 1; else hi = mid; }
    int s0 = lo; hi = n;
    while (lo < hi) { int mid = (lo + hi) >> 1; if (batch[mid] < g + 1) lo = mid + 1; else hi = mid; }
    float cnt = (float)(lo - s0);
    float inv = 1.f / fmaxf(cnt, 1.f);
    float s = bl[o];
    for (int c = 0; c < 128; ++c) s += sums[g * 128 + c] * inv * Wl[c * OUT_DIM + o];
    out[g * OUT_DIM + o] = s;
}

// ---------------- launch ----------------

extern "C" void kernel_launch(void* const* d_in, const int* in_sizes, int n_in,
                              void* d_out, int out_size, void* d_ws, size_t ws_size,
                              hipStream_t stream) {
    const float* x    = (const float*)d_in[0];
    const int*   ei   = (const int*)d_in[1];
    const int*   batch= (const int*)d_in[2];
    const float* Ws1  = (const float*)d_in[3];
    const float* Wd1  = (const float*)d_in[4];
    const float* as1  = (const float*)d_in[5];
    const float* ad1  = (const float*)d_in[6];
    const float* b1   = (const float*)d_in[7];
    const float* Ws2  = (const float*)d_in[8];
    const float* Wd2  = (const float*)d_in[9];
    const float* as2  = (const float*)d_in[10];
    const float* ad2  = (const float*)d_in[11];
    const float* b2   = (const float*)d_in[12];
    const float* Wl   = (const float*)d_in[13];
    const float* bl   = (const float*)d_in[14];
    float* out = (float*)d_out;

    char* p = (char*)d_ws;
    auto alloc = [&](size_t bytes) {
        void* r = (void*)p;
        p += (bytes + 255) & ~(size_t)255;
        return r;
    };
    int* exclT    = (int*)alloc(sizeof(int) * NREG * NB2);                     // 1.2 MB
    unsigned int* recs = (unsigned int*)alloc(sizeof(int) * (size_t)NREG * SC_EDGES); // 3.2 MB
    unsigned short* eids = (unsigned short*)alloc(sizeof(short) * (size_t)NB2 * EIDS_HALF); // 2.2 MB
    int2* rsre    = (int2*)alloc(sizeof(int2) * N_NODES);
    float* a_s    = (float*)alloc(sizeof(float) * N_NODES * 2);
    float* a_d    = (float*)alloc(sizeof(float) * N_NODES * 2);
    float* sums   = (float*)alloc(sizeof(float) * N_GRAPHS * 128);
    float* weffd1 = (float*)alloc(sizeof(float) * 128 * 2);
    float* weffd2 = (float*)alloc(sizeof(float) * 128 * 2);
    unsigned short* Wt1  = (unsigned short*)alloc(sizeof(short) * 128 * 128);
    unsigned short* Wt2  = (unsigned short*)alloc(sizeof(short) * 128 * 128);
    unsigned short* bufA = (unsigned short*)alloc(sizeof(short) * (size_t)N_NODES * F_DIM);
    unsigned short* bufB = (unsigned short*)alloc(sizeof(short) * (size_t)N_NODES * F_DIM);

    const int gemm_grid = (N_NODES + 63) / 64;            // 782 == NB2
    const int npairs    = N_NODES / 2;
    const int agg_grid  = (npairs + 3) / 4;

    // ---- CSR build + prep (fused) ----
    scatter_prep_kernel<<<NREG, 1024, 0, stream>>>(ei, Ws1, Ws2, Wd1, ad1, Wd2, ad2,
                                                   Wt1, Wt2, weffd1, weffd2,
                                                   (uint4*)sums, recs, exclT);

    // ---- layer 1 (gemm + bucketize fused) ----
    gemm1_bucketize_kernel<<<gemm_grid, 256, 0, stream>>>(x, Wt1, as1, weffd1,
                                                          recs, exclT,
                                                          bufA, a_s, a_d,
                                                          eids, rsre, N_NODES);
    aggregate_kernel<<<agg_grid, 256, 0, stream>>>(rsre, eids, a_s, a_d,
                                                   (const unsigned int*)bufA, b1,
                                                   (unsigned int*)bufB, npairs);

    // ---- layer 2 ----
    gemm_fused_bf16_kernel<<<gemm_grid, 256, 0, stream>>>(bufB, Wt2, as2, weffd2,
                                                          bufA, a_s, a_d, N_NODES);
    aggregate_kernel<<<agg_grid, 256, 0, stream>>>(rsre, eids, a_s, a_d,
                                                   (const unsigned int*)bufA, b2,
                                                   (unsigned int*)bufB, npairs);

    // ---- pool + linear ----
    pool_partial_kernel<<<POOL_BLOCKS, 256, 0, stream>>>(bufB, batch, sums, N_NODES);
    final_linear_kernel<<<(N_GRAPHS * OUT_DIM + 255) / 256, 256, 0, stream>>>(sums, batch, Wl, bl, out, N_NODES);
}